// Round 8
// baseline (2547.497 us; speedup 1.0000x reference)
//
#include <hip/hip_runtime.h>
#include <hip/hip_bf16.h>
#include <stdint.h>

// Problem dims
#define T_  48
#define B_  16
#define HW_ 768
#define D_  684
#define N_  256
#define A_  512

// Workspace layout (float offsets). Footprint <= proven 5445312 floats.
#define OFF_SZ     0u
#define OFF_SR     196608u
#define OFF_SH     393216u
#define OFF_UHZT   589824u    // gates1 weights [k][n] x3 (196608)
#define OFF_UHZ2T  786432u    // gates2 h-weights [k][n] x3 (196608)
#define OFF_G2HP   983040u    // DOUBLE-BUF Uh2.h1 partials [2][b][8][3][256] = 196608 -> 1179648
#define OFF_WAT    1179648u   // [k=256][a=512] (131072) -> 1310720
#define OFF_WCZT   1310720u   // [d=684][n=256] x3 (525312) -> 1836032
#define OFF_UAB    1836032u   // Ua bf16 [a=512][k=688] = 176128 -> 2012160
#define OFF_WAHP   2012160u   // Wa.h1 partials [b][8][512] = 65536 -> 2077696
#define OFF_H1     2077696u   // DOUBLE-BUF h1 [2][b][256] = 8192 -> 2085888
#define OFF_CTAB   2085888u   // (R7) conv gather table int[k=128][hw=768] = 98304 -> 2184192 (gap to KCB)
#define OFF_KCB    2186240u   // K_comb^T bf16 [a=512][k=128] = 32768 -> 2219008
#define OFF_G2CT   2219008u   // DOUBLE-BUF Wc.ct accum [2][b][3][256] = 24576 -> 2243584
#define OFF_AP     2275008u   // alpha_past B*HW (12288)
#define OFF_AUN    2287296u   // per-step e sums (atomic) B*HW (12288)
#define OFF_UACTX  2299584u   // Ua_ctx bf16 [b][hw][a]; end 5445312

// d_out offsets
#define OUT_H2 0u
#define OUT_CT 196608u
#define OUT_AL 721920u
#define OUT_AP 1311744u

typedef __attribute__((ext_vector_type(8))) short bf16x8;
typedef __attribute__((ext_vector_type(16))) float floatx16;

__device__ __forceinline__ float sigf(float x)  { return 1.f / (1.f + __expf(-x)); }
__device__ __forceinline__ float tanhf_(float x){ float e = __expf(2.f*x); return 1.f - 2.f/(e + 1.f); }
__device__ __forceinline__ float bfval(unsigned short u){ return __uint_as_float(((unsigned)u) << 16); }
__device__ __forceinline__ unsigned short f2bf(float f){
  unsigned int x = __float_as_uint(f);
  return (unsigned short)((x + 0x7fffu + ((x >> 16) & 1u)) >> 16);  // RNE
}

// ---------------- prep: weight transposes + Ua->bf16 + zero alpha_past + conv table ----------------
__global__ void k_prep(const float* __restrict__ Uhz, const float* __restrict__ Uhr, const float* __restrict__ Uhh,
                       const float* __restrict__ Uhz2, const float* __restrict__ Uhr2, const float* __restrict__ Uhh2,
                       const float* __restrict__ Wyz, const float* __restrict__ Wyr, const float* __restrict__ Wyh,
                       const float* __restrict__ Wa, const float* __restrict__ Wcz, const float* __restrict__ Wcr,
                       const float* __restrict__ Wch, const float* __restrict__ Ua, float* __restrict__ ws)
{
  int i = blockIdx.x * 256 + threadIdx.x;
  if (i < 589824) {                     // 9 x (256x256) -> [k][n]
    int m = i >> 16, rem = i & 65535, r = rem >> 8, c = rem & 255;
    const float* s;
    unsigned dst;
    switch (m) { case 0: s=Uhz;  dst=OFF_UHZT;           break;
                 case 1: s=Uhr;  dst=OFF_UHZT+65536u;    break;
                 case 2: s=Uhh;  dst=OFF_UHZT+131072u;   break;
                 case 3: s=Uhz2; dst=OFF_UHZ2T;          break;
                 case 4: s=Uhr2; dst=OFF_UHZ2T+65536u;   break;
                 case 5: s=Uhh2; dst=OFF_UHZ2T+131072u;  break;
                 case 6: s=Wyz;  dst=983040u;            break;  // scratch (embproj)
                 case 7: s=Wyr;  dst=1048576u;           break;
                 default: s=Wyh; dst=1114112u;           break;}
    ws[dst + c*256 + r] = s[rem];
  } else if (i < 720896) {              // Wa [512][256] -> WaT [256][512]
    int j = i - 589824, r = j >> 8, c = j & 255;
    ws[OFF_WAT + c*512 + r] = Wa[j];
  } else if (i < 1246208) {             // Wc* [256][684] -> [684][256]
    int j = i - 720896; int m = j / 175104; int rem = j - m*175104;
    int r = rem / 684, c = rem - r*684;
    const float* s = (m == 0) ? Wcz : (m == 1) ? Wcr : Wch;
    ws[OFF_WCZT + m*175104 + c*256 + r] = s[rem];
  } else if (i < 1596416) {             // Ua [512][684] fp32 -> bf16 [a][688]
    int j = i - 1246208; int a = j / 684, d = j - a*684;
    unsigned short* uab = (unsigned short*)(ws + OFF_UAB);
    uab[(size_t)a*688 + d] = f2bf(Ua[j]);
  } else if (i < 1598464) {             // UaB k-padding zeros
    int j = i - 1596416; int a = j >> 2, d = 684 + (j & 3);
    unsigned short* uab = (unsigned short*)(ws + OFF_UAB);
    uab[(size_t)a*688 + d] = 0;
  } else if (i < 1610752) {             // zero alpha_past
    ws[OFF_AP + (i - 1598464)] = 0.f;
  } else if (i < 1709056) {             // (R7) conv gather table [k=128][hw=768]
    int j = i - 1610752; int k = j / 768, hw = j - k*768;
    int off = -1;
    if (k < 121) {
      int hh = hw / 48, wwp = hw - hh*48;
      int kh = k / 11, kw = k - kh*11;
      int shh = hh + kh - 5, sww = wwp + kw - 5;
      if (shh >= 0 && shh < 16 && sww >= 0 && sww < 48) off = shh*48 + sww;
    }
    ((int*)(ws + OFF_CTAB))[j] = off;
  }
}

// ---------------- K_comb bf16 [a=512][k=128] ----------------
// (R1): one thread per output element; 256 blocks, coalesced Qw, fp32 acc.
__global__ void __launch_bounds__(256) k_kcomb(const float* __restrict__ Uf, const float* __restrict__ Qw,
                                               float* __restrict__ ws)
{
  unsigned short* kcb = (unsigned short*)(ws + OFF_KCB);
  int tid = threadIdx.x;
  int k = tid & 127, rr = tid >> 7;
  int a = blockIdx.x * 2 + rr;
  if (k >= 121) { kcb[(size_t)a*128 + k] = 0; return; }
  const float* uf = Uf + (size_t)a*512;
  float acc = 0.f;
  #pragma unroll 8
  for (int c = 0; c < 512; ++c) acc += uf[c] * Qw[c*121 + k];
  kcb[(size_t)a*128 + k] = f2bf(acc);
}

// ---------------- embedding projections ----------------
// (R3): grid 384 = rowchunk(48 of 16) x colchunk(8 of 32); block-internal 8-way k-split.
__global__ void __launch_bounds__(256) k_embproj(const float* __restrict__ emb, const float* __restrict__ bz,
                                                 const float* __restrict__ br, const float* __restrict__ bh,
                                                 float* __restrict__ ws)
{
  __shared__ __align__(16) float s_e[256 * 16];      // [m][r] 16 KB
  __shared__ float s_part[8][32][48];                // [kg][col][g*16+r] 48 KB
  int tid = threadIdx.x;
  int rc = blockIdx.x >> 3, cc = blockIdx.x & 7;
  int row0 = rc * 16, n0 = cc * 32;
  for (int i = tid; i < 4096; i += 256) { int r = i >> 8, m = i & 255; s_e[m*16 + r] = emb[(row0 + r)*256 + m]; }
  __syncthreads();
  int col = tid & 31, kg = tid >> 5;
  int n = n0 + col;
  float az[16], ar[16], ah[16];
  #pragma unroll
  for (int r = 0; r < 16; ++r) { az[r] = 0.f; ar[r] = 0.f; ah[r] = 0.f; }
  #pragma unroll 4
  for (int m = kg*32; m < kg*32 + 32; ++m) {
    float wz = ws[983040u + m*256 + n];
    float wr = ws[1048576u + m*256 + n];
    float wh = ws[1114112u + m*256 + n];
    const float4* ep = (const float4*)(s_e + m*16);
    #pragma unroll
    for (int rq = 0; rq < 4; ++rq) {
      float4 e4 = ep[rq];
      az[rq*4+0] += wz*e4.x; az[rq*4+1] += wz*e4.y; az[rq*4+2] += wz*e4.z; az[rq*4+3] += wz*e4.w;
      ar[rq*4+0] += wr*e4.x; ar[rq*4+1] += wr*e4.y; ar[rq*4+2] += wr*e4.z; ar[rq*4+3] += wr*e4.w;
      ah[rq*4+0] += wh*e4.x; ah[rq*4+1] += wh*e4.y; ah[rq*4+2] += wh*e4.z; ah[rq*4+3] += wh*e4.w;
    }
  }
  #pragma unroll
  for (int r = 0; r < 16; ++r) {
    s_part[kg][col][r]      = az[r];
    s_part[kg][col][16 + r] = ar[r];
    s_part[kg][col][32 + r] = ah[r];
  }
  __syncthreads();
  {
    int rcol = tid & 31, j0 = (tid >> 5) * 6;
    int rn = n0 + rcol;
    #pragma unroll
    for (int jj = 0; jj < 6; ++jj) {
      int j = j0 + jj;
      float v = 0.f;
      #pragma unroll
      for (int k8 = 0; k8 < 8; ++k8) v += s_part[k8][rcol][j];
      int g = j >> 4, r = j & 15;
      const float* bp = (g == 0) ? bz : (g == 1) ? br : bh;
      v += bp[rn];
      ws[g*196608u + (row0 + r)*256 + rn] = v;
    }
  }
}

// ---------------- Ua_ctx via bf16 MFMA ----------------
// (R6): grid 768, ah-MAJOR block order + 1-deep software prefetch.
__global__ void __launch_bounds__(256) k_uactx(const float* __restrict__ ctx, float* __restrict__ ws)
{
  int tid = threadIdx.x;
  int blk = blockIdx.x;
  int ah = blk / 384; int rem = blk % 384; int b = rem / 24; int ch = rem % 24;
  int hw0 = ch * 32;
  const unsigned short* uab = (const unsigned short*)(ws + OFF_UAB);
  int lane = tid & 63, w = tid >> 6;
  int c5 = lane & 31, q = lane >> 5;
  int nb = ah*256 + w*64;
  const float* cbase = ctx + (size_t)b*684*768 + hw0 + c5;   // + d*768
  floatx16 acc[2];
  #pragma unroll
  for (int nt = 0; nt < 2; ++nt)
    #pragma unroll
    for (int r = 0; r < 16; ++r) acc[nt][r] = 0.f;
  float av[8];
  #pragma unroll
  for (int e = 0; e < 8; ++e) av[e] = cbase[(size_t)(q*8 + e)*768];
  for (int kt = 0; kt < 43; ++kt) {
    bf16x8 af;
    #pragma unroll
    for (int e = 0; e < 8; ++e) af[e] = (short)f2bf(av[e]);
    if (kt < 42) {                       // prefetch kt+1 during MFMAs
      int d0 = (kt + 1)*16 + q*8;
      #pragma unroll
      for (int e = 0; e < 8; ++e) {
        int d = d0 + e;
        av[e] = (d < 684) ? cbase[(size_t)d*768] : 0.f;
      }
    }
    #pragma unroll
    for (int nt = 0; nt < 2; ++nt) {
      bf16x8 bf = *(const bf16x8*)(uab + (size_t)(nb + nt*32 + c5)*688 + kt*16 + q*8);
      acc[nt] = __builtin_amdgcn_mfma_f32_32x32x16_bf16(af, bf, acc[nt], 0, 0, 0);
    }
  }
  unsigned short* up = (unsigned short*)(ws + OFF_UACTX);
  #pragma unroll
  for (int nt = 0; nt < 2; ++nt) {
    int col = nb + nt*32 + c5;
    #pragma unroll
    for (int r = 0; r < 16; ++r) {
      int row32 = (r & 3) + 8*(r >> 2) + 4*q;
      int hw = hw0 + row32;
      up[((size_t)(b*768 + hw))*512 + col] = f2bf(acc[nt][r]);
    }
  }
}

// ---------------- step0: h1(0) -> H1[0], WAHP/G2HP[0] partials, zero AUN/G2CT[0] ----------------
// (R0): grid 128 = b(16) x q(8). Unchanged; writes the same buffer layouts as step1.
__global__ void __launch_bounds__(256) k_step0(const float* __restrict__ inits, const float* __restrict__ maskp,
                                               float* __restrict__ ws)
{
  __shared__ float s_h[256];
  __shared__ float s_part[3][8][32];
  __shared__ float s_h1[32];
  int tid = threadIdx.x;
  int b = blockIdx.x >> 3, q = blockIdx.x & 7;
  s_h[tid] = inits[b*256 + tid];
  if (q == 0) {
    for (int i = tid; i < 768; i += 256) ws[OFF_AUN + b*768 + i] = 0.f;
    #pragma unroll
    for (int g = 0; g < 3; ++g) ws[OFF_G2CT + (b*3 + g)*256 + tid] = 0.f;   // buf 0
  }
  __syncthreads();
  {
    int nl = tid & 31, kq = tid >> 5;
    int col = q*32 + nl;
    const float* Wz = ws + OFF_UHZT;
    const float* Wr = ws + OFF_UHZT + 65536u;
    const float* Wh = ws + OFF_UHZT + 131072u;
    float a0 = 0.f, a1 = 0.f, a2 = 0.f;
    #pragma unroll 8
    for (int k = kq*32; k < kq*32 + 32; ++k) {
      float hk = s_h[k];
      a0 += Wz[k*256 + col]*hk; a1 += Wr[k*256 + col]*hk; a2 += Wh[k*256 + col]*hk;
    }
    s_part[0][kq][nl] = a0; s_part[1][kq][nl] = a1; s_part[2][kq][nl] = a2;
  }
  __syncthreads();
  if (tid < 32) {
    float g0 = 0.f, g1 = 0.f, g2 = 0.f;
    #pragma unroll
    for (int j = 0; j < 8; ++j) { g0 += s_part[0][j][tid]; g1 += s_part[1][j][tid]; g2 += s_part[2][j][tid]; }
    int col = q*32 + tid;
    int ro = b*256 + col;                 // t = 0
    float z1 = sigf(g0 + ws[OFF_SZ + ro]);
    float r1 = sigf(g1 + ws[OFF_SR + ro]);
    float h1p = tanhf_(g2 * r1 + ws[OFF_SH + ro]);
    float m = maskp[b];                   // t = 0
    float h = s_h[col];
    float h1 = m*(z1*h + (1.f - z1)*h1p) + (1.f - m)*h;
    s_h1[tid] = h1;
    ws[OFF_H1 + b*256 + col] = h1;        // buf 0
  }
  __syncthreads();
  {
    float acc0 = 0.f, acc1 = 0.f;
    #pragma unroll 8
    for (int j = 0; j < 32; ++j) {
      float h1j = s_h1[j];
      acc0 += ws[OFF_WAT + (q*32 + j)*512 + tid]       * h1j;
      acc1 += ws[OFF_WAT + (q*32 + j)*512 + tid + 256] * h1j;
    }
    ws[OFF_WAHP + (size_t)(b*8 + q)*512 + tid]       = acc0;
    ws[OFF_WAHP + (size_t)(b*8 + q)*512 + tid + 256] = acc1;
  }
  #pragma unroll
  for (int g = 0; g < 3; ++g) {
    const float* Wb = ws + OFF_UHZ2T + g*65536u;
    float acc = 0.f;
    #pragma unroll 8
    for (int j = 0; j < 32; ++j) acc += Wb[(q*32 + j)*256 + tid] * s_h1[j];
    ws[OFF_G2HP + (size_t)((b*8 + q)*3 + g)*256 + tid] = acc;   // buf 0
  }
}

// ---------------- step1(t>=1): h2(t-1) combine + gates1(t) + h1(t) + partials ----------------
// RESTRUCTURED (R7): 512-thread blocks (grid 128 = b(16) x q(8)) for 2x TLP on the
// active CUs (old: 4 waves on ~128 CUs, half GPU idle, L2-latency exposed).
// gates1 split-k now 16 groups x 16k; WAHP one col/thread; G2HP strided 768/512.
// Same buffer layouts; fp32 k-partial reassociation only.
__global__ void __launch_bounds__(512) k_step1(int t, const float* __restrict__ maskp,
                                               const float* __restrict__ bz2, const float* __restrict__ br2,
                                               const float* __restrict__ bh2,
                                               float* __restrict__ out, float* __restrict__ ws)
{
  __shared__ float s_h[256];
  __shared__ float s_part[3][16][32];
  __shared__ float s_h1[32];
  int tid = threadIdx.x;
  int b = blockIdx.x >> 3, q = blockIdx.x & 7;
  const unsigned pr = (unsigned)((t - 1) & 1);
  const unsigned pw = (unsigned)(t & 1);
  // ---- Phase A: h2(t-1) combine (tid<256); zeroing (q==0, tid>=256) ----
  if (tid < 256) {
    int n = tid;
    float h1v = ws[OFF_H1 + pr*4096u + b*256 + n];
    float gz = ws[OFF_G2CT + pr*12288u + (b*3 + 0)*256 + n];
    float gr = ws[OFF_G2CT + pr*12288u + (b*3 + 1)*256 + n];
    float gc = ws[OFF_G2CT + pr*12288u + (b*3 + 2)*256 + n];
    float gu = 0.f;
    #pragma unroll
    for (int qq = 0; qq < 8; ++qq) {
      gz += ws[OFF_G2HP + pr*98304u + (size_t)((b*8 + qq)*3 + 0)*256 + n];
      gr += ws[OFF_G2HP + pr*98304u + (size_t)((b*8 + qq)*3 + 1)*256 + n];
      gu += ws[OFF_G2HP + pr*98304u + (size_t)((b*8 + qq)*3 + 2)*256 + n];
    }
    float z2 = sigf(gz + bz2[n]);
    float r2 = sigf(gr + br2[n]);
    float h2p = tanhf_(gc + (gu + bh2[n]) * r2);
    float h2 = z2*h1v + (1.f - z2)*h2p;
    float m = maskp[(t-1)*16 + b];
    float hv = m*h2 + (1.f - m)*h1v;
    if (q == 0) out[OUT_H2 + (size_t)((t-1)*16 + b)*256 + n] = hv;
    s_h[n] = hv;
  } else if (q == 0) {
    int base = tid - 256;
    #pragma unroll
    for (int it = 0; it < 3; ++it) {
      int idx = base + it*256;
      ws[OFF_AUN + b*768 + idx] = 0.f;
      ws[OFF_G2CT + pw*12288u + b*768 + idx] = 0.f;   // [b][3][256] contiguous 768
    }
  }
  __syncthreads();
  // ---- Phase B: gates1 for cols q*32..q*32+31, 16-way split-k ----
  {
    int nl = tid & 31, kq = tid >> 5;   // kq 0..15
    int col = q*32 + nl;
    const float* Wz = ws + OFF_UHZT;
    const float* Wr = ws + OFF_UHZT + 65536u;
    const float* Wh = ws + OFF_UHZT + 131072u;
    float a0 = 0.f, a1 = 0.f, a2 = 0.f;
    #pragma unroll
    for (int k = kq*16; k < kq*16 + 16; ++k) {
      float hk = s_h[k];
      a0 += Wz[k*256 + col]*hk; a1 += Wr[k*256 + col]*hk; a2 += Wh[k*256 + col]*hk;
    }
    s_part[0][kq][nl] = a0; s_part[1][kq][nl] = a1; s_part[2][kq][nl] = a2;
  }
  __syncthreads();
  if (tid < 32) {
    float g0 = 0.f, g1 = 0.f, g2 = 0.f;
    #pragma unroll
    for (int j = 0; j < 16; ++j) { g0 += s_part[0][j][tid]; g1 += s_part[1][j][tid]; g2 += s_part[2][j][tid]; }
    int col = q*32 + tid;
    int ro = (t*16 + b)*256 + col;
    float z1 = sigf(g0 + ws[OFF_SZ + ro]);
    float r1 = sigf(g1 + ws[OFF_SR + ro]);
    float h1p = tanhf_(g2 * r1 + ws[OFF_SH + ro]);
    float m = maskp[t*16 + b];
    float h = s_h[col];
    float h1 = m*(z1*h + (1.f - z1)*h1p) + (1.f - m)*h;
    s_h1[tid] = h1;
    ws[OFF_H1 + pw*4096u + b*256 + col] = h1;
  }
  __syncthreads();
  // ---- Phase C: WAHP over own 32 k's, one col per thread ----
  {
    float acc = 0.f;
    #pragma unroll 8
    for (int j = 0; j < 32; ++j) acc += ws[OFF_WAT + (q*32 + j)*512 + tid] * s_h1[j];
    ws[OFF_WAHP + (size_t)(b*8 + q)*512 + tid] = acc;
  }
  // ---- Phase D: G2HP[pw] (Uh2 . h1 partials), 768 outputs over 512 threads ----
  for (int idx = tid; idx < 768; idx += 512) {
    int g = idx >> 8, n = idx & 255;
    const float* Wb = ws + OFF_UHZ2T + g*65536u;
    float acc = 0.f;
    #pragma unroll 8
    for (int j = 0; j < 32; ++j) acc += Wb[(q*32 + j)*256 + n] * s_h1[j];
    ws[OFF_G2HP + pw*98304u + (size_t)((b*8 + q)*3 + g)*256 + n] = acc;
  }
}

// ---------------- cover: bf16 MFMA GEMM + tanh + va partial e ----------------
// grid 384 = b(16) x mt(12) x nt2(2). (R7): conv-gather via precomputed table.
__global__ void __launch_bounds__(256) k_cover(const float* __restrict__ va,
                                               const float* __restrict__ Uab, const float* __restrict__ Ufb,
                                               float* __restrict__ ws)
{
  __shared__ unsigned short sA[64 * 136];
  __shared__ float sWah[512];
  __shared__ float sVa[512];
  int tid = threadIdx.x;
  int blk = blockIdx.x;
  int b = blk / 24; int chA = blk % 24; int mt = chA >> 1; int nt2 = chA & 1;
  for (int i = tid; i < 512; i += 256) {
    float v = Uab[i] + Ufb[i];
    #pragma unroll
    for (int qq = 0; qq < 8; ++qq) v += ws[OFF_WAHP + (size_t)(b*8 + qq)*512 + i];
    sWah[i] = v; sVa[i] = va[i];
  }
  const float* ap = ws + OFF_AP + b*768;
  const int* ctab = (const int*)(ws + OFF_CTAB);
  for (int idx = tid; idx < 64*128; idx += 256) {
    int r = idx & 63, k = idx >> 6;
    int off = ctab[k*768 + mt*64 + r];
    float v = (off >= 0) ? ap[off] : 0.f;
    sA[r*136 + k] = f2bf(v);
  }
  __syncthreads();
  int lane = tid & 63; int w = tid >> 6; int mw = w >> 1; int nw = w & 1;
  int c5 = lane & 31; int q = lane >> 5;
  bf16x8 af[8];
  {
    int m = mw*32 + c5;
    #pragma unroll
    for (int ks = 0; ks < 8; ++ks)
      af[ks] = *(const bf16x8*)(sA + m*136 + ks*16 + q*8);
  }
  const unsigned short* kct = (const unsigned short*)(ws + OFF_KCB);
  const unsigned short* uact = (const unsigned short*)(ws + OFF_UACTX);
  float e_part[16];
  #pragma unroll
  for (int r = 0; r < 16; ++r) e_part[r] = 0.f;
  for (int sp = 0; sp < 2; ++sp) {
    int n_base = nt2*256 + nw*128 + sp*64;
    floatx16 acc[2];
    #pragma unroll
    for (int r = 0; r < 16; ++r) { acc[0][r] = 0.f; acc[1][r] = 0.f; }
    const bf16x8* kb0 = (const bf16x8*)(kct + (size_t)(n_base + c5)*128 + q*8);
    const bf16x8* kb1 = (const bf16x8*)(kct + (size_t)(n_base + 32 + c5)*128 + q*8);
    #pragma unroll
    for (int ks = 0; ks < 8; ++ks) {
      bf16x8 b0 = kb0[ks*2];
      bf16x8 b1 = kb1[ks*2];
      acc[0] = __builtin_amdgcn_mfma_f32_32x32x16_bf16(af[ks], b0, acc[0], 0, 0, 0);
      acc[1] = __builtin_amdgcn_mfma_f32_32x32x16_bf16(af[ks], b1, acc[1], 0, 0, 0);
    }
    #pragma unroll
    for (int half = 0; half < 2; ++half) {
      int col = n_base + half*32 + c5;
      float vav = sVa[col], wah = sWah[col];
      #pragma unroll
      for (int r = 0; r < 16; ++r) {
        int row32 = (r & 3) + 8*(r >> 2) + 4*q;
        int hw = mt*64 + mw*32 + row32;
        float x = acc[half][r] + wah + bfval(uact[((size_t)(b*768 + hw))*512 + col]);
        e_part[r] += vav * tanhf_(x);
      }
    }
  }
  #pragma unroll
  for (int r = 0; r < 16; ++r) {
    float v = e_part[r];
    v += __shfl_xor(v, 1); v += __shfl_xor(v, 2); v += __shfl_xor(v, 4);
    v += __shfl_xor(v, 8); v += __shfl_xor(v, 16);
    e_part[r] = v;
  }
  if (c5 == 0) {
    #pragma unroll
    for (int r = 0; r < 16; ++r) {
      int row32 = (r & 3) + 8*(r >> 2) + 4*q;
      int hw = mt*64 + mw*32 + row32;
      atomicAdd(&ws[OFF_AUN + b*768 + hw], e_part[r]);
    }
  }
}

// ---------------- alpha: softmax + AP + outputs + ct + Wc.ct -> G2CT[t&1] ----------------
// grid 352 = b(16) x dc(22)
__global__ void __launch_bounds__(256) k_alpha(int t, const float* __restrict__ ctx, const float* __restrict__ cmask,
                                               const float* __restrict__ vab,
                                               float* __restrict__ out, float* __restrict__ ws)
{
  __shared__ __align__(16) float s_al[768];
  __shared__ float s_red[4];
  __shared__ float s_ct[32];
  int tid = threadIdx.x;
  int b = blockIdx.x / 22, dc = blockIdx.x % 22;
  const unsigned pw = (unsigned)(t & 1);
  float vb = vab[0];
  float local = 0.f;
  for (int i = tid; i < 768; i += 256) {
    float e = ws[OFF_AUN + b*768 + i] + vb;
    float un = __expf(e) * cmask[b*768 + i];
    s_al[i] = un; local += un;
  }
  local += __shfl_xor(local, 1); local += __shfl_xor(local, 2); local += __shfl_xor(local, 4);
  local += __shfl_xor(local, 8); local += __shfl_xor(local, 16); local += __shfl_xor(local, 32);
  if ((tid & 63) == 0) s_red[tid >> 6] = local;
  __syncthreads();
  float inv = 1.f / (s_red[0] + s_red[1] + s_red[2] + s_red[3]);
  if (dc == 0) {
    float* outA = out + OUT_AL + (size_t)(t*16 + b)*768;
    float* outP = out + OUT_AP + (size_t)(t*16 + b)*768;
    for (int i = tid; i < 768; i += 256) {
      float av = s_al[i] * inv;
      float np = ws[OFF_AP + b*768 + i] + av;
      ws[OFF_AP + b*768 + i] = np;
      outA[i] = av; outP[i] = np;
    }
  }
  {
    int dl = tid >> 3, qq = tid & 7;
    int d = dc*32 + dl;
    if (d < 684) {
      const float4* cp  = (const float4*)(ctx + ((size_t)(b*684 + d))*768);
      const float4* alp = (const float4*)s_al;
      float s = 0.f;
      #pragma unroll 8
      for (int i = 0; i < 24; ++i) {
        float4 cv = cp[i*8 + qq]; float4 av = alp[i*8 + qq];
        s += cv.x*av.x + cv.y*av.y + cv.z*av.z + cv.w*av.w;
      }
      s += __shfl_xor(s, 1); s += __shfl_xor(s, 2); s += __shfl_xor(s, 4);
      s *= inv;
      if (qq == 0) {
        out[OUT_CT + (size_t)(t*16 + b)*684 + d] = s;
        s_ct[dl] = s;
      }
    } else if (qq == 0) {
      s_ct[dl] = 0.f;
    }
  }
  __syncthreads();
  {
    int d0 = dc*32;
    int jm = 684 - d0; if (jm > 32) jm = 32;
    #pragma unroll
    for (int g = 0; g < 3; ++g) {
      const float* Wb = ws + OFF_WCZT + g*175104u;
      float acc = 0.f;
      for (int j = 0; j < jm; ++j) acc += Wb[(d0 + j)*256 + tid] * s_ct[j];
      atomicAdd(&ws[OFF_G2CT + pw*12288u + (size_t)(b*3 + g)*256 + tid], acc);
    }
  }
}

// ---------------- final combine for t=47 ----------------
__global__ void k_final(const float* __restrict__ maskp, const float* __restrict__ bz2,
                        const float* __restrict__ br2, const float* __restrict__ bh2,
                        float* __restrict__ out, float* __restrict__ ws)
{
  int b = blockIdx.x, n = threadIdx.x;
  const unsigned pr = 1u;  // 47 & 1
  float h1v = ws[OFF_H1 + pr*4096u + b*256 + n];
  float gz = ws[OFF_G2CT + pr*12288u + (b*3 + 0)*256 + n];
  float gr = ws[OFF_G2CT + pr*12288u + (b*3 + 1)*256 + n];
  float gc = ws[OFF_G2CT + pr*12288u + (b*3 + 2)*256 + n];
  float gu = 0.f;
  #pragma unroll
  for (int qq = 0; qq < 8; ++qq) {
    gz += ws[OFF_G2HP + pr*98304u + (size_t)((b*8 + qq)*3 + 0)*256 + n];
    gr += ws[OFF_G2HP + pr*98304u + (size_t)((b*8 + qq)*3 + 1)*256 + n];
    gu += ws[OFF_G2HP + pr*98304u + (size_t)((b*8 + qq)*3 + 2)*256 + n];
  }
  float z2 = sigf(gz + bz2[n]);
  float r2 = sigf(gr + br2[n]);
  float h2p = tanhf_(gc + (gu + bh2[n]) * r2);
  float h2 = z2*h1v + (1.f - z2)*h2p;
  float m = maskp[47*16 + b];
  out[OUT_H2 + (size_t)(47*16 + b)*256 + n] = m*h2 + (1.f - m)*h1v;
}

extern "C" void kernel_launch(void* const* d_in, const int* in_sizes, int n_in,
                              void* d_out, int out_size, void* d_ws, size_t ws_size,
                              hipStream_t stream)
{
  const float* emb   = (const float*)d_in[0];
  const float* maskp = (const float*)d_in[1];
  const float* ctx   = (const float*)d_in[2];
  const float* cmask = (const float*)d_in[3];
  const float* inits = (const float*)d_in[4];
  const float* Ua    = (const float*)d_in[5];
  const float* Uab   = (const float*)d_in[6];
  const float* Wa    = (const float*)d_in[7];
  const float* Qw    = (const float*)d_in[8];
  const float* Uf    = (const float*)d_in[9];
  const float* Ufb   = (const float*)d_in[10];
  const float* va    = (const float*)d_in[11];
  const float* vab   = (const float*)d_in[12];
  const float* Wyz   = (const float*)d_in[13];
  const float* Wyzb  = (const float*)d_in[14];
  const float* Wyr   = (const float*)d_in[15];
  const float* Wyrb  = (const float*)d_in[16];
  const float* Wyh   = (const float*)d_in[17];
  const float* Wyhb  = (const float*)d_in[18];
  const float* Uhz   = (const float*)d_in[19];
  const float* Uhr   = (const float*)d_in[20];
  const float* Uhh   = (const float*)d_in[21];
  const float* Wcz   = (const float*)d_in[22];
  const float* Wcr   = (const float*)d_in[23];
  const float* Wch   = (const float*)d_in[24];
  const float* Uhz2  = (const float*)d_in[25];
  const float* Uhz2b = (const float*)d_in[26];
  const float* Uhr2  = (const float*)d_in[27];
  const float* Uhr2b = (const float*)d_in[28];
  const float* Uhh2  = (const float*)d_in[29];
  const float* Uhh2b = (const float*)d_in[30];
  float* out = (float*)d_out;
  float* ws  = (float*)d_ws;

  k_prep<<<dim3(6676), dim3(256), 0, stream>>>(Uhz, Uhr, Uhh, Uhz2, Uhr2, Uhh2,
                                               Wyz, Wyr, Wyh, Wa, Wcz, Wcr, Wch, Ua, ws);
  k_kcomb<<<dim3(256), dim3(256), 0, stream>>>(Uf, Qw, ws);
  k_embproj<<<dim3(384), dim3(256), 0, stream>>>(emb, Wyzb, Wyrb, Wyhb, ws);
  k_uactx<<<dim3(768), dim3(256), 0, stream>>>(ctx, ws);
  k_step0<<<dim3(128), dim3(256), 0, stream>>>(inits, maskp, ws);

  k_cover<<<dim3(384), dim3(256), 0, stream>>>(va, Uab, Ufb, ws);
  k_alpha<<<dim3(352), dim3(256), 0, stream>>>(0, ctx, cmask, vab, out, ws);
  for (int t = 1; t < 48; ++t) {
    k_step1<<<dim3(128), dim3(512), 0, stream>>>(t, maskp, Uhz2b, Uhr2b, Uhh2b, out, ws);
    k_cover<<<dim3(384), dim3(256), 0, stream>>>(va, Uab, Ufb, ws);
    k_alpha<<<dim3(352), dim3(256), 0, stream>>>(t, ctx, cmask, vab, out, ws);
  }
  k_final<<<dim3(16), dim3(256), 0, stream>>>(maskp, Uhz2b, Uhr2b, Uhh2b, out, ws);
  (void)in_sizes; (void)n_in; (void)out_size; (void)ws_size;
}

// Round 9
// 2456.165 us; speedup vs baseline: 1.0372x; 1.0372x over previous
//
#include <hip/hip_runtime.h>
#include <hip/hip_bf16.h>
#include <stdint.h>

// Problem dims
#define T_  48
#define B_  16
#define HW_ 768
#define D_  684
#define N_  256
#define A_  512

// Workspace layout (float offsets). Footprint <= proven 5445312 floats.
#define OFF_SZ     0u
#define OFF_SR     196608u
#define OFF_SH     393216u
#define OFF_UHZT   589824u    // gates1 weights [k][n] x3 (196608)
#define OFF_UHZ2T  786432u    // gates2 h-weights [k][n] x3 (196608)
#define OFF_G2HP   983040u    // DOUBLE-BUF Uh2.h1 partials [2][b][8][3][256] = 196608 -> 1179648
#define OFF_WAT    1179648u   // [k=256][a=512] (131072) -> 1310720
#define OFF_WCZT   1310720u   // [d=684][n=256] x3 (525312) -> 1836032
#define OFF_UAB    1836032u   // Ua bf16 [a=512][k=688] = 176128 -> 2012160
#define OFF_WAHP   2012160u   // Wa.h1 partials [b][8][512] = 65536 -> 2077696
#define OFF_H1     2077696u   // DOUBLE-BUF h1 [2][b][256] = 8192 -> 2085888
#define OFF_KCB    2186240u   // K_comb^T bf16 [a=512][k=128] = 32768 -> 2219008
#define OFF_G2CT   2219008u   // DOUBLE-BUF Wc.ct accum [2][b][3][256] = 24576 -> 2243584
#define OFF_AP     2275008u   // alpha_past B*HW (12288)
#define OFF_AUN    2287296u   // per-step e sums (atomic) B*HW (12288)
#define OFF_UACTX  2299584u   // Ua_ctx bf16 [b][hw][a]; end 5445312

// d_out offsets
#define OUT_H2 0u
#define OUT_CT 196608u
#define OUT_AL 721920u
#define OUT_AP 1311744u

typedef __attribute__((ext_vector_type(8))) short bf16x8;
typedef __attribute__((ext_vector_type(16))) float floatx16;

__device__ __forceinline__ float sigf(float x)  { return 1.f / (1.f + __expf(-x)); }
__device__ __forceinline__ float tanhf_(float x){ float e = __expf(2.f*x); return 1.f - 2.f/(e + 1.f); }
__device__ __forceinline__ float bfval(unsigned short u){ return __uint_as_float(((unsigned)u) << 16); }
__device__ __forceinline__ unsigned short f2bf(float f){
  unsigned int x = __float_as_uint(f);
  return (unsigned short)((x + 0x7fffu + ((x >> 16) & 1u)) >> 16);  // RNE
}

// ---------------- prep: weight transposes + Ua->bf16 + zero alpha_past ----------------
__global__ void k_prep(const float* __restrict__ Uhz, const float* __restrict__ Uhr, const float* __restrict__ Uhh,
                       const float* __restrict__ Uhz2, const float* __restrict__ Uhr2, const float* __restrict__ Uhh2,
                       const float* __restrict__ Wyz, const float* __restrict__ Wyr, const float* __restrict__ Wyh,
                       const float* __restrict__ Wa, const float* __restrict__ Wcz, const float* __restrict__ Wcr,
                       const float* __restrict__ Wch, const float* __restrict__ Ua, float* __restrict__ ws)
{
  int i = blockIdx.x * 256 + threadIdx.x;
  if (i < 589824) {                     // 9 x (256x256) -> [k][n]
    int m = i >> 16, rem = i & 65535, r = rem >> 8, c = rem & 255;
    const float* s;
    unsigned dst;
    switch (m) { case 0: s=Uhz;  dst=OFF_UHZT;           break;
                 case 1: s=Uhr;  dst=OFF_UHZT+65536u;    break;
                 case 2: s=Uhh;  dst=OFF_UHZT+131072u;   break;
                 case 3: s=Uhz2; dst=OFF_UHZ2T;          break;
                 case 4: s=Uhr2; dst=OFF_UHZ2T+65536u;   break;
                 case 5: s=Uhh2; dst=OFF_UHZ2T+131072u;  break;
                 case 6: s=Wyz;  dst=983040u;            break;  // scratch (embproj)
                 case 7: s=Wyr;  dst=1048576u;           break;
                 default: s=Wyh; dst=1114112u;           break;}
    ws[dst + c*256 + r] = s[rem];
  } else if (i < 720896) {              // Wa [512][256] -> WaT [256][512]
    int j = i - 589824, r = j >> 8, c = j & 255;
    ws[OFF_WAT + c*512 + r] = Wa[j];
  } else if (i < 1246208) {             // Wc* [256][684] -> [684][256]
    int j = i - 720896; int m = j / 175104; int rem = j - m*175104;
    int r = rem / 684, c = rem - r*684;
    const float* s = (m == 0) ? Wcz : (m == 1) ? Wcr : Wch;
    ws[OFF_WCZT + m*175104 + c*256 + r] = s[rem];
  } else if (i < 1596416) {             // Ua [512][684] fp32 -> bf16 [a][688]
    int j = i - 1246208; int a = j / 684, d = j - a*684;
    unsigned short* uab = (unsigned short*)(ws + OFF_UAB);
    uab[(size_t)a*688 + d] = f2bf(Ua[j]);
  } else if (i < 1598464) {             // UaB k-padding zeros
    int j = i - 1596416; int a = j >> 2, d = 684 + (j & 3);
    unsigned short* uab = (unsigned short*)(ws + OFF_UAB);
    uab[(size_t)a*688 + d] = 0;
  } else if (i < 1610752) {             // zero alpha_past
    ws[OFF_AP + (i - 1598464)] = 0.f;
  }
}

// ---------------- K_comb bf16 [a=512][k=128] ----------------
// (R1): one thread per output element; 256 blocks, coalesced Qw, fp32 acc.
__global__ void __launch_bounds__(256) k_kcomb(const float* __restrict__ Uf, const float* __restrict__ Qw,
                                               float* __restrict__ ws)
{
  unsigned short* kcb = (unsigned short*)(ws + OFF_KCB);
  int tid = threadIdx.x;
  int k = tid & 127, rr = tid >> 7;
  int a = blockIdx.x * 2 + rr;
  if (k >= 121) { kcb[(size_t)a*128 + k] = 0; return; }
  const float* uf = Uf + (size_t)a*512;
  float acc = 0.f;
  #pragma unroll 8
  for (int c = 0; c < 512; ++c) acc += uf[c] * Qw[c*121 + k];
  kcb[(size_t)a*128 + k] = f2bf(acc);
}

// ---------------- embedding projections ----------------
// (R3): grid 384 = rowchunk(48 of 16) x colchunk(8 of 32); block-internal 8-way k-split.
__global__ void __launch_bounds__(256) k_embproj(const float* __restrict__ emb, const float* __restrict__ bz,
                                                 const float* __restrict__ br, const float* __restrict__ bh,
                                                 float* __restrict__ ws)
{
  __shared__ __align__(16) float s_e[256 * 16];      // [m][r] 16 KB
  __shared__ float s_part[8][32][48];                // [kg][col][g*16+r] 48 KB
  int tid = threadIdx.x;
  int rc = blockIdx.x >> 3, cc = blockIdx.x & 7;
  int row0 = rc * 16, n0 = cc * 32;
  for (int i = tid; i < 4096; i += 256) { int r = i >> 8, m = i & 255; s_e[m*16 + r] = emb[(row0 + r)*256 + m]; }
  __syncthreads();
  int col = tid & 31, kg = tid >> 5;
  int n = n0 + col;
  float az[16], ar[16], ah[16];
  #pragma unroll
  for (int r = 0; r < 16; ++r) { az[r] = 0.f; ar[r] = 0.f; ah[r] = 0.f; }
  #pragma unroll 4
  for (int m = kg*32; m < kg*32 + 32; ++m) {
    float wz = ws[983040u + m*256 + n];
    float wr = ws[1048576u + m*256 + n];
    float wh = ws[1114112u + m*256 + n];
    const float4* ep = (const float4*)(s_e + m*16);
    #pragma unroll
    for (int rq = 0; rq < 4; ++rq) {
      float4 e4 = ep[rq];
      az[rq*4+0] += wz*e4.x; az[rq*4+1] += wz*e4.y; az[rq*4+2] += wz*e4.z; az[rq*4+3] += wz*e4.w;
      ar[rq*4+0] += wr*e4.x; ar[rq*4+1] += wr*e4.y; ar[rq*4+2] += wr*e4.z; ar[rq*4+3] += wr*e4.w;
      ah[rq*4+0] += wh*e4.x; ah[rq*4+1] += wh*e4.y; ah[rq*4+2] += wh*e4.z; ah[rq*4+3] += wh*e4.w;
    }
  }
  #pragma unroll
  for (int r = 0; r < 16; ++r) {
    s_part[kg][col][r]      = az[r];
    s_part[kg][col][16 + r] = ar[r];
    s_part[kg][col][32 + r] = ah[r];
  }
  __syncthreads();
  {
    int rcol = tid & 31, j0 = (tid >> 5) * 6;
    int rn = n0 + rcol;
    #pragma unroll
    for (int jj = 0; jj < 6; ++jj) {
      int j = j0 + jj;
      float v = 0.f;
      #pragma unroll
      for (int k8 = 0; k8 < 8; ++k8) v += s_part[k8][rcol][j];
      int g = j >> 4, r = j & 15;
      const float* bp = (g == 0) ? bz : (g == 1) ? br : bh;
      v += bp[rn];
      ws[g*196608u + (row0 + r)*256 + rn] = v;
    }
  }
}

// ---------------- Ua_ctx via bf16 MFMA ----------------
// (R6 structure, R8): grid 768, ah-MAJOR block order, now 2-DEEP software prefetch
// (named av0/av1 buffers, no runtime-indexed arrays -> no scratch). R6's 1-deep kept
// only 8 loads in flight/wave; at 25% occupancy that under-hides HBM/L3 latency
// (measured 650 GB/s on a 19.3 MB fetch). 2-deep doubles MLP. Same tiling/numerics.
__global__ void __launch_bounds__(256) k_uactx(const float* __restrict__ ctx, float* __restrict__ ws)
{
  int tid = threadIdx.x;
  int blk = blockIdx.x;
  int ah = blk / 384; int rem = blk % 384; int b = rem / 24; int ch = rem % 24;
  int hw0 = ch * 32;
  const unsigned short* uab = (const unsigned short*)(ws + OFF_UAB);
  int lane = tid & 63, w = tid >> 6;
  int c5 = lane & 31, q = lane >> 5;
  int nb = ah*256 + w*64;
  const float* cbase = ctx + (size_t)b*684*768 + hw0 + c5;   // + d*768
  floatx16 acc[2];
  #pragma unroll
  for (int nt = 0; nt < 2; ++nt)
    #pragma unroll
    for (int r = 0; r < 16; ++r) acc[nt][r] = 0.f;
  float av0[8], av1[8];
  // preload kt=0 -> av0, kt=1 -> av1 (d <= 31 < 684: no guard)
  #pragma unroll
  for (int e = 0; e < 8; ++e) av0[e] = cbase[(size_t)(q*8 + e)*768];
  #pragma unroll
  for (int e = 0; e < 8; ++e) av1[e] = cbase[(size_t)(16 + q*8 + e)*768];
  for (int kt = 0; kt < 43; kt += 2) {
    // ---- even kt: consume av0, prefetch kt+2 into av0 ----
    {
      bf16x8 af;
      #pragma unroll
      for (int e = 0; e < 8; ++e) af[e] = (short)f2bf(av0[e]);
      if (kt + 2 < 43) {
        int d0 = (kt + 2)*16 + q*8;
        #pragma unroll
        for (int e = 0; e < 8; ++e) {
          int d = d0 + e;
          av0[e] = (d < 684) ? cbase[(size_t)d*768] : 0.f;
        }
      }
      #pragma unroll
      for (int nt = 0; nt < 2; ++nt) {
        bf16x8 bf = *(const bf16x8*)(uab + (size_t)(nb + nt*32 + c5)*688 + kt*16 + q*8);
        acc[nt] = __builtin_amdgcn_mfma_f32_32x32x16_bf16(af, bf, acc[nt], 0, 0, 0);
      }
    }
    // ---- odd kt+1: consume av1, prefetch kt+3 into av1 ----
    if (kt + 1 < 43) {
      bf16x8 af;
      #pragma unroll
      for (int e = 0; e < 8; ++e) af[e] = (short)f2bf(av1[e]);
      if (kt + 3 < 43) {
        int d0 = (kt + 3)*16 + q*8;
        #pragma unroll
        for (int e = 0; e < 8; ++e) {
          int d = d0 + e;
          av1[e] = (d < 684) ? cbase[(size_t)d*768] : 0.f;
        }
      }
      #pragma unroll
      for (int nt = 0; nt < 2; ++nt) {
        bf16x8 bf = *(const bf16x8*)(uab + (size_t)(nb + nt*32 + c5)*688 + (kt + 1)*16 + q*8);
        acc[nt] = __builtin_amdgcn_mfma_f32_32x32x16_bf16(af, bf, acc[nt], 0, 0, 0);
      }
    }
  }
  unsigned short* up = (unsigned short*)(ws + OFF_UACTX);
  #pragma unroll
  for (int nt = 0; nt < 2; ++nt) {
    int col = nb + nt*32 + c5;
    #pragma unroll
    for (int r = 0; r < 16; ++r) {
      int row32 = (r & 3) + 8*(r >> 2) + 4*q;
      int hw = hw0 + row32;
      up[((size_t)(b*768 + hw))*512 + col] = f2bf(acc[nt][r]);
    }
  }
}

// ---------------- step0: h1(0) -> H1[0], WAHP/G2HP[0] partials, zero AUN/G2CT[0] ----------------
// (R0): grid 128 = b(16) x q(8).
__global__ void __launch_bounds__(256) k_step0(const float* __restrict__ inits, const float* __restrict__ maskp,
                                               float* __restrict__ ws)
{
  __shared__ float s_h[256];
  __shared__ float s_part[3][8][32];
  __shared__ float s_h1[32];
  int tid = threadIdx.x;
  int b = blockIdx.x >> 3, q = blockIdx.x & 7;
  s_h[tid] = inits[b*256 + tid];
  if (q == 0) {
    for (int i = tid; i < 768; i += 256) ws[OFF_AUN + b*768 + i] = 0.f;
    #pragma unroll
    for (int g = 0; g < 3; ++g) ws[OFF_G2CT + (b*3 + g)*256 + tid] = 0.f;   // buf 0
  }
  __syncthreads();
  {
    int nl = tid & 31, kq = tid >> 5;
    int col = q*32 + nl;
    const float* Wz = ws + OFF_UHZT;
    const float* Wr = ws + OFF_UHZT + 65536u;
    const float* Wh = ws + OFF_UHZT + 131072u;
    float a0 = 0.f, a1 = 0.f, a2 = 0.f;
    #pragma unroll 8
    for (int k = kq*32; k < kq*32 + 32; ++k) {
      float hk = s_h[k];
      a0 += Wz[k*256 + col]*hk; a1 += Wr[k*256 + col]*hk; a2 += Wh[k*256 + col]*hk;
    }
    s_part[0][kq][nl] = a0; s_part[1][kq][nl] = a1; s_part[2][kq][nl] = a2;
  }
  __syncthreads();
  if (tid < 32) {
    float g0 = 0.f, g1 = 0.f, g2 = 0.f;
    #pragma unroll
    for (int j = 0; j < 8; ++j) { g0 += s_part[0][j][tid]; g1 += s_part[1][j][tid]; g2 += s_part[2][j][tid]; }
    int col = q*32 + tid;
    int ro = b*256 + col;                 // t = 0
    float z1 = sigf(g0 + ws[OFF_SZ + ro]);
    float r1 = sigf(g1 + ws[OFF_SR + ro]);
    float h1p = tanhf_(g2 * r1 + ws[OFF_SH + ro]);
    float m = maskp[b];                   // t = 0
    float h = s_h[col];
    float h1 = m*(z1*h + (1.f - z1)*h1p) + (1.f - m)*h;
    s_h1[tid] = h1;
    ws[OFF_H1 + b*256 + col] = h1;        // buf 0
  }
  __syncthreads();
  {
    float acc0 = 0.f, acc1 = 0.f;
    #pragma unroll 8
    for (int j = 0; j < 32; ++j) {
      float h1j = s_h1[j];
      acc0 += ws[OFF_WAT + (q*32 + j)*512 + tid]       * h1j;
      acc1 += ws[OFF_WAT + (q*32 + j)*512 + tid + 256] * h1j;
    }
    ws[OFF_WAHP + (size_t)(b*8 + q)*512 + tid]       = acc0;
    ws[OFF_WAHP + (size_t)(b*8 + q)*512 + tid + 256] = acc1;
  }
  #pragma unroll
  for (int g = 0; g < 3; ++g) {
    const float* Wb = ws + OFF_UHZ2T + g*65536u;
    float acc = 0.f;
    #pragma unroll 8
    for (int j = 0; j < 32; ++j) acc += Wb[(q*32 + j)*256 + tid] * s_h1[j];
    ws[OFF_G2HP + (size_t)((b*8 + q)*3 + g)*256 + tid] = acc;   // buf 0
  }
}

// ---------------- step1(t>=1): h2(t-1) combine + gates1(t) + h1(t) + partials ----------------
// (R6 revert): grid 128 = b(16) x q(8), 256 threads. R7's 512-thread variant regressed
// (+83 us total): same 128-CU coverage but 8-wave sync cost + halved gates1 ILP.
__global__ void __launch_bounds__(256) k_step1(int t, const float* __restrict__ maskp,
                                               const float* __restrict__ bz2, const float* __restrict__ br2,
                                               const float* __restrict__ bh2,
                                               float* __restrict__ out, float* __restrict__ ws)
{
  __shared__ float s_h[256];
  __shared__ float s_part[3][8][32];
  __shared__ float s_h1[32];
  int tid = threadIdx.x;
  int b = blockIdx.x >> 3, q = blockIdx.x & 7;
  const unsigned pr = (unsigned)((t - 1) & 1);
  const unsigned pw = (unsigned)(t & 1);
  {
    int n = tid;
    float h1v = ws[OFF_H1 + pr*4096u + b*256 + n];
    float gz = ws[OFF_G2CT + pr*12288u + (b*3 + 0)*256 + n];
    float gr = ws[OFF_G2CT + pr*12288u + (b*3 + 1)*256 + n];
    float gc = ws[OFF_G2CT + pr*12288u + (b*3 + 2)*256 + n];
    float gu = 0.f;
    #pragma unroll
    for (int qq = 0; qq < 8; ++qq) {
      gz += ws[OFF_G2HP + pr*98304u + (size_t)((b*8 + qq)*3 + 0)*256 + n];
      gr += ws[OFF_G2HP + pr*98304u + (size_t)((b*8 + qq)*3 + 1)*256 + n];
      gu += ws[OFF_G2HP + pr*98304u + (size_t)((b*8 + qq)*3 + 2)*256 + n];
    }
    float z2 = sigf(gz + bz2[n]);
    float r2 = sigf(gr + br2[n]);
    float h2p = tanhf_(gc + (gu + bh2[n]) * r2);
    float h2 = z2*h1v + (1.f - z2)*h2p;
    float m = maskp[(t-1)*16 + b];
    float hv = m*h2 + (1.f - m)*h1v;
    if (q == 0) out[OUT_H2 + (size_t)((t-1)*16 + b)*256 + n] = hv;
    s_h[n] = hv;
  }
  if (q == 0) {
    for (int i = tid; i < 768; i += 256) ws[OFF_AUN + b*768 + i] = 0.f;
    #pragma unroll
    for (int g = 0; g < 3; ++g) ws[OFF_G2CT + pw*12288u + (b*3 + g)*256 + tid] = 0.f;
  }
  __syncthreads();
  {
    int nl = tid & 31, kq = tid >> 5;
    int col = q*32 + nl;
    const float* Wz = ws + OFF_UHZT;
    const float* Wr = ws + OFF_UHZT + 65536u;
    const float* Wh = ws + OFF_UHZT + 131072u;
    float a0 = 0.f, a1 = 0.f, a2 = 0.f;
    #pragma unroll 8
    for (int k = kq*32; k < kq*32 + 32; ++k) {
      float hk = s_h[k];
      a0 += Wz[k*256 + col]*hk; a1 += Wr[k*256 + col]*hk; a2 += Wh[k*256 + col]*hk;
    }
    s_part[0][kq][nl] = a0; s_part[1][kq][nl] = a1; s_part[2][kq][nl] = a2;
  }
  __syncthreads();
  if (tid < 32) {
    float g0 = 0.f, g1 = 0.f, g2 = 0.f;
    #pragma unroll
    for (int j = 0; j < 8; ++j) { g0 += s_part[0][j][tid]; g1 += s_part[1][j][tid]; g2 += s_part[2][j][tid]; }
    int col = q*32 + tid;
    int ro = (t*16 + b)*256 + col;
    float z1 = sigf(g0 + ws[OFF_SZ + ro]);
    float r1 = sigf(g1 + ws[OFF_SR + ro]);
    float h1p = tanhf_(g2 * r1 + ws[OFF_SH + ro]);
    float m = maskp[t*16 + b];
    float h = s_h[col];
    float h1 = m*(z1*h + (1.f - z1)*h1p) + (1.f - m)*h;
    s_h1[tid] = h1;
    ws[OFF_H1 + pw*4096u + b*256 + col] = h1;
  }
  __syncthreads();
  {
    float acc0 = 0.f, acc1 = 0.f;
    #pragma unroll 8
    for (int j = 0; j < 32; ++j) {
      float h1j = s_h1[j];
      acc0 += ws[OFF_WAT + (q*32 + j)*512 + tid]       * h1j;
      acc1 += ws[OFF_WAT + (q*32 + j)*512 + tid + 256] * h1j;
    }
    ws[OFF_WAHP + (size_t)(b*8 + q)*512 + tid]       = acc0;
    ws[OFF_WAHP + (size_t)(b*8 + q)*512 + tid + 256] = acc1;
  }
  #pragma unroll
  for (int g = 0; g < 3; ++g) {
    const float* Wb = ws + OFF_UHZ2T + g*65536u;
    float acc = 0.f;
    #pragma unroll 8
    for (int j = 0; j < 32; ++j) acc += Wb[(q*32 + j)*256 + tid] * s_h1[j];
    ws[OFF_G2HP + pw*98304u + (size_t)((b*8 + q)*3 + g)*256 + tid] = acc;
  }
}

// ---------------- cover: bf16 MFMA GEMM + tanh + va partial e ----------------
// (R6 revert): grid 384 = b(16) x mt(12) x nt2(2), compute-based conv gather.
__global__ void __launch_bounds__(256) k_cover(const float* __restrict__ va,
                                               const float* __restrict__ Uab, const float* __restrict__ Ufb,
                                               float* __restrict__ ws)
{
  __shared__ unsigned short sA[64 * 136];
  __shared__ float sWah[512];
  __shared__ float sVa[512];
  int tid = threadIdx.x;
  int blk = blockIdx.x;
  int b = blk / 24; int chA = blk % 24; int mt = chA >> 1; int nt2 = chA & 1;
  for (int i = tid; i < 512; i += 256) {
    float v = Uab[i] + Ufb[i];
    #pragma unroll
    for (int qq = 0; qq < 8; ++qq) v += ws[OFF_WAHP + (size_t)(b*8 + qq)*512 + i];
    sWah[i] = v; sVa[i] = va[i];
  }
  const float* ap = ws + OFF_AP + b*768;
  for (int idx = tid; idx < 64*128; idx += 256) {
    int r = idx & 63, k = idx >> 6;
    int hw = mt*64 + r; int hh = hw / 48; int wwp = hw - hh*48;
    float v = 0.f;
    if (k < 121) {
      int kh = k / 11, kw = k - kh*11;
      int shh = hh + kh - 5, sww = wwp + kw - 5;
      if (shh >= 0 && shh < 16 && sww >= 0 && sww < 48) v = ap[shh*48 + sww];
    }
    sA[r*136 + k] = f2bf(v);
  }
  __syncthreads();
  int lane = tid & 63; int w = tid >> 6; int mw = w >> 1; int nw = w & 1;
  int c5 = lane & 31; int q = lane >> 5;
  bf16x8 af[8];
  {
    int m = mw*32 + c5;
    #pragma unroll
    for (int ks = 0; ks < 8; ++ks)
      af[ks] = *(const bf16x8*)(sA + m*136 + ks*16 + q*8);
  }
  const unsigned short* kct = (const unsigned short*)(ws + OFF_KCB);
  const unsigned short* uact = (const unsigned short*)(ws + OFF_UACTX);
  float e_part[16];
  #pragma unroll
  for (int r = 0; r < 16; ++r) e_part[r] = 0.f;
  for (int sp = 0; sp < 2; ++sp) {
    int n_base = nt2*256 + nw*128 + sp*64;
    floatx16 acc[2];
    #pragma unroll
    for (int r = 0; r < 16; ++r) { acc[0][r] = 0.f; acc[1][r] = 0.f; }
    const bf16x8* kb0 = (const bf16x8*)(kct + (size_t)(n_base + c5)*128 + q*8);
    const bf16x8* kb1 = (const bf16x8*)(kct + (size_t)(n_base + 32 + c5)*128 + q*8);
    #pragma unroll
    for (int ks = 0; ks < 8; ++ks) {
      bf16x8 b0 = kb0[ks*2];
      bf16x8 b1 = kb1[ks*2];
      acc[0] = __builtin_amdgcn_mfma_f32_32x32x16_bf16(af[ks], b0, acc[0], 0, 0, 0);
      acc[1] = __builtin_amdgcn_mfma_f32_32x32x16_bf16(af[ks], b1, acc[1], 0, 0, 0);
    }
    #pragma unroll
    for (int half = 0; half < 2; ++half) {
      int col = n_base + half*32 + c5;
      float vav = sVa[col], wah = sWah[col];
      #pragma unroll
      for (int r = 0; r < 16; ++r) {
        int row32 = (r & 3) + 8*(r >> 2) + 4*q;
        int hw = mt*64 + mw*32 + row32;
        float x = acc[half][r] + wah + bfval(uact[((size_t)(b*768 + hw))*512 + col]);
        e_part[r] += vav * tanhf_(x);
      }
    }
  }
  #pragma unroll
  for (int r = 0; r < 16; ++r) {
    float v = e_part[r];
    v += __shfl_xor(v, 1); v += __shfl_xor(v, 2); v += __shfl_xor(v, 4);
    v += __shfl_xor(v, 8); v += __shfl_xor(v, 16);
    e_part[r] = v;
  }
  if (c5 == 0) {
    #pragma unroll
    for (int r = 0; r < 16; ++r) {
      int row32 = (r & 3) + 8*(r >> 2) + 4*q;
      int hw = mt*64 + mw*32 + row32;
      atomicAdd(&ws[OFF_AUN + b*768 + hw], e_part[r]);
    }
  }
}

// ---------------- alpha: softmax + AP + outputs + ct + Wc.ct -> G2CT[t&1] ----------------
// grid 352 = b(16) x dc(22)
__global__ void __launch_bounds__(256) k_alpha(int t, const float* __restrict__ ctx, const float* __restrict__ cmask,
                                               const float* __restrict__ vab,
                                               float* __restrict__ out, float* __restrict__ ws)
{
  __shared__ __align__(16) float s_al[768];
  __shared__ float s_red[4];
  __shared__ float s_ct[32];
  int tid = threadIdx.x;
  int b = blockIdx.x / 22, dc = blockIdx.x % 22;
  const unsigned pw = (unsigned)(t & 1);
  float vb = vab[0];
  float local = 0.f;
  for (int i = tid; i < 768; i += 256) {
    float e = ws[OFF_AUN + b*768 + i] + vb;
    float un = __expf(e) * cmask[b*768 + i];
    s_al[i] = un; local += un;
  }
  local += __shfl_xor(local, 1); local += __shfl_xor(local, 2); local += __shfl_xor(local, 4);
  local += __shfl_xor(local, 8); local += __shfl_xor(local, 16); local += __shfl_xor(local, 32);
  if ((tid & 63) == 0) s_red[tid >> 6] = local;
  __syncthreads();
  float inv = 1.f / (s_red[0] + s_red[1] + s_red[2] + s_red[3]);
  if (dc == 0) {
    float* outA = out + OUT_AL + (size_t)(t*16 + b)*768;
    float* outP = out + OUT_AP + (size_t)(t*16 + b)*768;
    for (int i = tid; i < 768; i += 256) {
      float av = s_al[i] * inv;
      float np = ws[OFF_AP + b*768 + i] + av;
      ws[OFF_AP + b*768 + i] = np;
      outA[i] = av; outP[i] = np;
    }
  }
  {
    int dl = tid >> 3, qq = tid & 7;
    int d = dc*32 + dl;
    if (d < 684) {
      const float4* cp  = (const float4*)(ctx + ((size_t)(b*684 + d))*768);
      const float4* alp = (const float4*)s_al;
      float s = 0.f;
      #pragma unroll 8
      for (int i = 0; i < 24; ++i) {
        float4 cv = cp[i*8 + qq]; float4 av = alp[i*8 + qq];
        s += cv.x*av.x + cv.y*av.y + cv.z*av.z + cv.w*av.w;
      }
      s += __shfl_xor(s, 1); s += __shfl_xor(s, 2); s += __shfl_xor(s, 4);
      s *= inv;
      if (qq == 0) {
        out[OUT_CT + (size_t)(t*16 + b)*684 + d] = s;
        s_ct[dl] = s;
      }
    } else if (qq == 0) {
      s_ct[dl] = 0.f;
    }
  }
  __syncthreads();
  {
    int d0 = dc*32;
    int jm = 684 - d0; if (jm > 32) jm = 32;
    #pragma unroll
    for (int g = 0; g < 3; ++g) {
      const float* Wb = ws + OFF_WCZT + g*175104u;
      float acc = 0.f;
      for (int j = 0; j < jm; ++j) acc += Wb[(d0 + j)*256 + tid] * s_ct[j];
      atomicAdd(&ws[OFF_G2CT + pw*12288u + (size_t)(b*3 + g)*256 + tid], acc);
    }
  }
}

// ---------------- final combine for t=47 ----------------
__global__ void k_final(const float* __restrict__ maskp, const float* __restrict__ bz2,
                        const float* __restrict__ br2, const float* __restrict__ bh2,
                        float* __restrict__ out, float* __restrict__ ws)
{
  int b = blockIdx.x, n = threadIdx.x;
  const unsigned pr = 1u;  // 47 & 1
  float h1v = ws[OFF_H1 + pr*4096u + b*256 + n];
  float gz = ws[OFF_G2CT + pr*12288u + (b*3 + 0)*256 + n];
  float gr = ws[OFF_G2CT + pr*12288u + (b*3 + 1)*256 + n];
  float gc = ws[OFF_G2CT + pr*12288u + (b*3 + 2)*256 + n];
  float gu = 0.f;
  #pragma unroll
  for (int qq = 0; qq < 8; ++qq) {
    gz += ws[OFF_G2HP + pr*98304u + (size_t)((b*8 + qq)*3 + 0)*256 + n];
    gr += ws[OFF_G2HP + pr*98304u + (size_t)((b*8 + qq)*3 + 1)*256 + n];
    gu += ws[OFF_G2HP + pr*98304u + (size_t)((b*8 + qq)*3 + 2)*256 + n];
  }
  float z2 = sigf(gz + bz2[n]);
  float r2 = sigf(gr + br2[n]);
  float h2p = tanhf_(gc + (gu + bh2[n]) * r2);
  float h2 = z2*h1v + (1.f - z2)*h2p;
  float m = maskp[47*16 + b];
  out[OUT_H2 + (size_t)(47*16 + b)*256 + n] = m*h2 + (1.f - m)*h1v;
}

extern "C" void kernel_launch(void* const* d_in, const int* in_sizes, int n_in,
                              void* d_out, int out_size, void* d_ws, size_t ws_size,
                              hipStream_t stream)
{
  const float* emb   = (const float*)d_in[0];
  const float* maskp = (const float*)d_in[1];
  const float* ctx   = (const float*)d_in[2];
  const float* cmask = (const float*)d_in[3];
  const float* inits = (const float*)d_in[4];
  const float* Ua    = (const float*)d_in[5];
  const float* Uab   = (const float*)d_in[6];
  const float* Wa    = (const float*)d_in[7];
  const float* Qw    = (const float*)d_in[8];
  const float* Uf    = (const float*)d_in[9];
  const float* Ufb   = (const float*)d_in[10];
  const float* va    = (const float*)d_in[11];
  const float* vab   = (const float*)d_in[12];
  const float* Wyz   = (const float*)d_in[13];
  const float* Wyzb  = (const float*)d_in[14];
  const float* Wyr   = (const float*)d_in[15];
  const float* Wyrb  = (const float*)d_in[16];
  const float* Wyh   = (const float*)d_in[17];
  const float* Wyhb  = (const float*)d_in[18];
  const float* Uhz   = (const float*)d_in[19];
  const float* Uhr   = (const float*)d_in[20];
  const float* Uhh   = (const float*)d_in[21];
  const float* Wcz   = (const float*)d_in[22];
  const float* Wcr   = (const float*)d_in[23];
  const float* Wch   = (const float*)d_in[24];
  const float* Uhz2  = (const float*)d_in[25];
  const float* Uhz2b = (const float*)d_in[26];
  const float* Uhr2  = (const float*)d_in[27];
  const float* Uhr2b = (const float*)d_in[28];
  const float* Uhh2  = (const float*)d_in[29];
  const float* Uhh2b = (const float*)d_in[30];
  float* out = (float*)d_out;
  float* ws  = (float*)d_ws;

  k_prep<<<dim3(6292), dim3(256), 0, stream>>>(Uhz, Uhr, Uhh, Uhz2, Uhr2, Uhh2,
                                               Wyz, Wyr, Wyh, Wa, Wcz, Wcr, Wch, Ua, ws);
  k_kcomb<<<dim3(256), dim3(256), 0, stream>>>(Uf, Qw, ws);
  k_embproj<<<dim3(384), dim3(256), 0, stream>>>(emb, Wyzb, Wyrb, Wyhb, ws);
  k_uactx<<<dim3(768), dim3(256), 0, stream>>>(ctx, ws);
  k_step0<<<dim3(128), dim3(256), 0, stream>>>(inits, maskp, ws);

  k_cover<<<dim3(384), dim3(256), 0, stream>>>(va, Uab, Ufb, ws);
  k_alpha<<<dim3(352), dim3(256), 0, stream>>>(0, ctx, cmask, vab, out, ws);
  for (int t = 1; t < 48; ++t) {
    k_step1<<<dim3(128), dim3(256), 0, stream>>>(t, maskp, Uhz2b, Uhr2b, Uhh2b, out, ws);
    k_cover<<<dim3(384), dim3(256), 0, stream>>>(va, Uab, Ufb, ws);
    k_alpha<<<dim3(352), dim3(256), 0, stream>>>(t, ctx, cmask, vab, out, ws);
  }
  k_final<<<dim3(16), dim3(256), 0, stream>>>(maskp, Uhz2b, Uhr2b, Uhh2b, out, ws);
  (void)in_sizes; (void)n_in; (void)out_size; (void)ws_size;
}

// Round 10
// 2226.005 us; speedup vs baseline: 1.1444x; 1.1034x over previous
//
#include <hip/hip_runtime.h>
#include <hip/hip_bf16.h>
#include <stdint.h>

// Problem dims
#define T_  48
#define B_  16
#define HW_ 768
#define D_  684
#define N_  256
#define A_  512

// Workspace layout (float offsets). Footprint <= proven 5445312 floats.
#define OFF_SZ     0u
#define OFF_SR     196608u
#define OFF_SH     393216u
#define OFF_UHZT   589824u    // gates1 weights [k][n] x3 (196608)
#define OFF_UHZ2T  786432u    // gates2 h-weights [k][n] x3 (196608)
#define OFF_G2HP   983040u    // DOUBLE-BUF Uh2.h1 partials [2][b][8][3][256] = 196608 -> 1179648
#define OFF_WAT    1179648u   // [k=256][a=512] (131072) -> 1310720
#define OFF_WCZT   1310720u   // [d=684][n=256] x3 (525312) -> 1836032
#define OFF_UAB    1836032u   // Ua bf16 [a=512][k=688] = 176128 -> 2012160
#define OFF_WAHP   2012160u   // Wa.h1 partials [b][8][512] = 65536 -> 2077696
#define OFF_H1     2077696u   // DOUBLE-BUF h1 [2][b][256] = 8192 -> 2085888
#define OFF_KCB    2186240u   // K_comb^T bf16 [a=512][k=128] = 32768 -> 2219008
#define OFF_G2CT   2219008u   // DOUBLE-BUF Wc.ct accum [2][b][3][256] = 24576 -> 2243584
#define OFF_AP     2275008u   // alpha_past B*HW (12288)
#define OFF_AUN    2287296u   // per-step e sums (atomic) B*HW (12288)
#define OFF_UACTX  2299584u   // Ua_ctx bf16 [b][hw][a]; end 5445312

// d_out offsets
#define OUT_H2 0u
#define OUT_CT 196608u
#define OUT_AL 721920u
#define OUT_AP 1311744u

typedef __attribute__((ext_vector_type(8))) short bf16x8;
typedef __attribute__((ext_vector_type(16))) float floatx16;

__device__ __forceinline__ float sigf(float x)  { return 1.f / (1.f + __expf(-x)); }
__device__ __forceinline__ float tanhf_(float x){ float e = __expf(2.f*x); return 1.f - 2.f/(e + 1.f); }
__device__ __forceinline__ float bfval(unsigned short u){ return __uint_as_float(((unsigned)u) << 16); }
__device__ __forceinline__ unsigned short f2bf(float f){
  unsigned int x = __float_as_uint(f);
  return (unsigned short)((x + 0x7fffu + ((x >> 16) & 1u)) >> 16);  // RNE
}

// ---------------- prep: weight transposes + Ua->bf16 + zero alpha_past ----------------
__global__ void k_prep(const float* __restrict__ Uhz, const float* __restrict__ Uhr, const float* __restrict__ Uhh,
                       const float* __restrict__ Uhz2, const float* __restrict__ Uhr2, const float* __restrict__ Uhh2,
                       const float* __restrict__ Wyz, const float* __restrict__ Wyr, const float* __restrict__ Wyh,
                       const float* __restrict__ Wa, const float* __restrict__ Wcz, const float* __restrict__ Wcr,
                       const float* __restrict__ Wch, const float* __restrict__ Ua, float* __restrict__ ws)
{
  int i = blockIdx.x * 256 + threadIdx.x;
  if (i < 589824) {                     // 9 x (256x256) -> [k][n]
    int m = i >> 16, rem = i & 65535, r = rem >> 8, c = rem & 255;
    const float* s;
    unsigned dst;
    switch (m) { case 0: s=Uhz;  dst=OFF_UHZT;           break;
                 case 1: s=Uhr;  dst=OFF_UHZT+65536u;    break;
                 case 2: s=Uhh;  dst=OFF_UHZT+131072u;   break;
                 case 3: s=Uhz2; dst=OFF_UHZ2T;          break;
                 case 4: s=Uhr2; dst=OFF_UHZ2T+65536u;   break;
                 case 5: s=Uhh2; dst=OFF_UHZ2T+131072u;  break;
                 case 6: s=Wyz;  dst=983040u;            break;  // scratch (embproj)
                 case 7: s=Wyr;  dst=1048576u;           break;
                 default: s=Wyh; dst=1114112u;           break;}
    ws[dst + c*256 + r] = s[rem];
  } else if (i < 720896) {              // Wa [512][256] -> WaT [256][512]
    int j = i - 589824, r = j >> 8, c = j & 255;
    ws[OFF_WAT + c*512 + r] = Wa[j];
  } else if (i < 1246208) {             // Wc* [256][684] -> [684][256]
    int j = i - 720896; int m = j / 175104; int rem = j - m*175104;
    int r = rem / 684, c = rem - r*684;
    const float* s = (m == 0) ? Wcz : (m == 1) ? Wcr : Wch;
    ws[OFF_WCZT + m*175104 + c*256 + r] = s[rem];
  } else if (i < 1596416) {             // Ua [512][684] fp32 -> bf16 [a][688]
    int j = i - 1246208; int a = j / 684, d = j - a*684;
    unsigned short* uab = (unsigned short*)(ws + OFF_UAB);
    uab[(size_t)a*688 + d] = f2bf(Ua[j]);
  } else if (i < 1598464) {             // UaB k-padding zeros
    int j = i - 1596416; int a = j >> 2, d = 684 + (j & 3);
    unsigned short* uab = (unsigned short*)(ws + OFF_UAB);
    uab[(size_t)a*688 + d] = 0;
  } else if (i < 1610752) {             // zero alpha_past
    ws[OFF_AP + (i - 1598464)] = 0.f;
  }
}

// ---------------- K_comb bf16 [a=512][k=128] ----------------
// (R1): one thread per output element; 256 blocks, coalesced Qw, fp32 acc.
__global__ void __launch_bounds__(256) k_kcomb(const float* __restrict__ Uf, const float* __restrict__ Qw,
                                               float* __restrict__ ws)
{
  unsigned short* kcb = (unsigned short*)(ws + OFF_KCB);
  int tid = threadIdx.x;
  int k = tid & 127, rr = tid >> 7;
  int a = blockIdx.x * 2 + rr;
  if (k >= 121) { kcb[(size_t)a*128 + k] = 0; return; }
  const float* uf = Uf + (size_t)a*512;
  float acc = 0.f;
  #pragma unroll 8
  for (int c = 0; c < 512; ++c) acc += uf[c] * Qw[c*121 + k];
  kcb[(size_t)a*128 + k] = f2bf(acc);
}

// ---------------- embedding projections ----------------
// (R3): grid 384 = rowchunk(48 of 16) x colchunk(8 of 32); block-internal 8-way k-split.
__global__ void __launch_bounds__(256) k_embproj(const float* __restrict__ emb, const float* __restrict__ bz,
                                                 const float* __restrict__ br, const float* __restrict__ bh,
                                                 float* __restrict__ ws)
{
  __shared__ __align__(16) float s_e[256 * 16];      // [m][r] 16 KB
  __shared__ float s_part[8][32][48];                // [kg][col][g*16+r] 48 KB
  int tid = threadIdx.x;
  int rc = blockIdx.x >> 3, cc = blockIdx.x & 7;
  int row0 = rc * 16, n0 = cc * 32;
  for (int i = tid; i < 4096; i += 256) { int r = i >> 8, m = i & 255; s_e[m*16 + r] = emb[(row0 + r)*256 + m]; }
  __syncthreads();
  int col = tid & 31, kg = tid >> 5;
  int n = n0 + col;
  float az[16], ar[16], ah[16];
  #pragma unroll
  for (int r = 0; r < 16; ++r) { az[r] = 0.f; ar[r] = 0.f; ah[r] = 0.f; }
  #pragma unroll 4
  for (int m = kg*32; m < kg*32 + 32; ++m) {
    float wz = ws[983040u + m*256 + n];
    float wr = ws[1048576u + m*256 + n];
    float wh = ws[1114112u + m*256 + n];
    const float4* ep = (const float4*)(s_e + m*16);
    #pragma unroll
    for (int rq = 0; rq < 4; ++rq) {
      float4 e4 = ep[rq];
      az[rq*4+0] += wz*e4.x; az[rq*4+1] += wz*e4.y; az[rq*4+2] += wz*e4.z; az[rq*4+3] += wz*e4.w;
      ar[rq*4+0] += wr*e4.x; ar[rq*4+1] += wr*e4.y; ar[rq*4+2] += wr*e4.z; ar[rq*4+3] += wr*e4.w;
      ah[rq*4+0] += wh*e4.x; ah[rq*4+1] += wh*e4.y; ah[rq*4+2] += wh*e4.z; ah[rq*4+3] += wh*e4.w;
    }
  }
  #pragma unroll
  for (int r = 0; r < 16; ++r) {
    s_part[kg][col][r]      = az[r];
    s_part[kg][col][16 + r] = ar[r];
    s_part[kg][col][32 + r] = ah[r];
  }
  __syncthreads();
  {
    int rcol = tid & 31, j0 = (tid >> 5) * 6;
    int rn = n0 + rcol;
    #pragma unroll
    for (int jj = 0; jj < 6; ++jj) {
      int j = j0 + jj;
      float v = 0.f;
      #pragma unroll
      for (int k8 = 0; k8 < 8; ++k8) v += s_part[k8][rcol][j];
      int g = j >> 4, r = j & 15;
      const float* bp = (g == 0) ? bz : (g == 1) ? br : bh;
      v += bp[rn];
      ws[g*196608u + (row0 + r)*256 + rn] = v;
    }
  }
}

// ---------------- Ua_ctx via bf16 MFMA ----------------
// (R6, reverted from R8): grid 768, ah-MAJOR block order + 1-deep software prefetch.
// R8's 2-deep prefetch regressed (48-51 -> 59-63 us; VALUBusy 25->33%): the limiter
// is not in-flight-load count. Keep the counter-verified 1-deep version.
__global__ void __launch_bounds__(256) k_uactx(const float* __restrict__ ctx, float* __restrict__ ws)
{
  int tid = threadIdx.x;
  int blk = blockIdx.x;
  int ah = blk / 384; int rem = blk % 384; int b = rem / 24; int ch = rem % 24;
  int hw0 = ch * 32;
  const unsigned short* uab = (const unsigned short*)(ws + OFF_UAB);
  int lane = tid & 63, w = tid >> 6;
  int c5 = lane & 31, q = lane >> 5;
  int nb = ah*256 + w*64;
  const float* cbase = ctx + (size_t)b*684*768 + hw0 + c5;   // + d*768
  floatx16 acc[2];
  #pragma unroll
  for (int nt = 0; nt < 2; ++nt)
    #pragma unroll
    for (int r = 0; r < 16; ++r) acc[nt][r] = 0.f;
  // prefetch kt=0 (d = q*8+e <= 15 < 684, no guard)
  float av[8];
  #pragma unroll
  for (int e = 0; e < 8; ++e) av[e] = cbase[(size_t)(q*8 + e)*768];
  for (int kt = 0; kt < 43; ++kt) {
    bf16x8 af;
    #pragma unroll
    for (int e = 0; e < 8; ++e) af[e] = (short)f2bf(av[e]);
    if (kt < 42) {                       // prefetch kt+1 during MFMAs
      int d0 = (kt + 1)*16 + q*8;
      #pragma unroll
      for (int e = 0; e < 8; ++e) {
        int d = d0 + e;
        av[e] = (d < 684) ? cbase[(size_t)d*768] : 0.f;
      }
    }
    #pragma unroll
    for (int nt = 0; nt < 2; ++nt) {
      bf16x8 bf = *(const bf16x8*)(uab + (size_t)(nb + nt*32 + c5)*688 + kt*16 + q*8);
      acc[nt] = __builtin_amdgcn_mfma_f32_32x32x16_bf16(af, bf, acc[nt], 0, 0, 0);
    }
  }
  unsigned short* up = (unsigned short*)(ws + OFF_UACTX);
  #pragma unroll
  for (int nt = 0; nt < 2; ++nt) {
    int col = nb + nt*32 + c5;
    #pragma unroll
    for (int r = 0; r < 16; ++r) {
      int row32 = (r & 3) + 8*(r >> 2) + 4*q;
      int hw = hw0 + row32;
      up[((size_t)(b*768 + hw))*512 + col] = f2bf(acc[nt][r]);
    }
  }
}

// ---------------- step0: h1(0) -> H1[0], WAHP/G2HP[0] partials, zero AUN/G2CT[0] ----------------
// (R0): grid 128 = b(16) x q(8).
__global__ void __launch_bounds__(256) k_step0(const float* __restrict__ inits, const float* __restrict__ maskp,
                                               float* __restrict__ ws)
{
  __shared__ float s_h[256];
  __shared__ float s_part[3][8][32];
  __shared__ float s_h1[32];
  int tid = threadIdx.x;
  int b = blockIdx.x >> 3, q = blockIdx.x & 7;
  s_h[tid] = inits[b*256 + tid];
  if (q == 0) {
    for (int i = tid; i < 768; i += 256) ws[OFF_AUN + b*768 + i] = 0.f;
    #pragma unroll
    for (int g = 0; g < 3; ++g) ws[OFF_G2CT + (b*3 + g)*256 + tid] = 0.f;   // buf 0
  }
  __syncthreads();
  {
    int nl = tid & 31, kq = tid >> 5;
    int col = q*32 + nl;
    const float* Wz = ws + OFF_UHZT;
    const float* Wr = ws + OFF_UHZT + 65536u;
    const float* Wh = ws + OFF_UHZT + 131072u;
    float a0 = 0.f, a1 = 0.f, a2 = 0.f;
    #pragma unroll 8
    for (int k = kq*32; k < kq*32 + 32; ++k) {
      float hk = s_h[k];
      a0 += Wz[k*256 + col]*hk; a1 += Wr[k*256 + col]*hk; a2 += Wh[k*256 + col]*hk;
    }
    s_part[0][kq][nl] = a0; s_part[1][kq][nl] = a1; s_part[2][kq][nl] = a2;
  }
  __syncthreads();
  if (tid < 32) {
    float g0 = 0.f, g1 = 0.f, g2 = 0.f;
    #pragma unroll
    for (int j = 0; j < 8; ++j) { g0 += s_part[0][j][tid]; g1 += s_part[1][j][tid]; g2 += s_part[2][j][tid]; }
    int col = q*32 + tid;
    int ro = b*256 + col;                 // t = 0
    float z1 = sigf(g0 + ws[OFF_SZ + ro]);
    float r1 = sigf(g1 + ws[OFF_SR + ro]);
    float h1p = tanhf_(g2 * r1 + ws[OFF_SH + ro]);
    float m = maskp[b];                   // t = 0
    float h = s_h[col];
    float h1 = m*(z1*h + (1.f - z1)*h1p) + (1.f - m)*h;
    s_h1[tid] = h1;
    ws[OFF_H1 + b*256 + col] = h1;        // buf 0
  }
  __syncthreads();
  {
    float acc0 = 0.f, acc1 = 0.f;
    #pragma unroll 8
    for (int j = 0; j < 32; ++j) {
      float h1j = s_h1[j];
      acc0 += ws[OFF_WAT + (q*32 + j)*512 + tid]       * h1j;
      acc1 += ws[OFF_WAT + (q*32 + j)*512 + tid + 256] * h1j;
    }
    ws[OFF_WAHP + (size_t)(b*8 + q)*512 + tid]       = acc0;
    ws[OFF_WAHP + (size_t)(b*8 + q)*512 + tid + 256] = acc1;
  }
  #pragma unroll
  for (int g = 0; g < 3; ++g) {
    const float* Wb = ws + OFF_UHZ2T + g*65536u;
    float acc = 0.f;
    #pragma unroll 8
    for (int j = 0; j < 32; ++j) acc += Wb[(q*32 + j)*256 + tid] * s_h1[j];
    ws[OFF_G2HP + (size_t)((b*8 + q)*3 + g)*256 + tid] = acc;   // buf 0
  }
}

// ---------------- step1(t>=1): h2(t-1) combine + gates1(t) + h1(t) + partials ----------------
// (R6): grid 128 = b(16) x q(8), 256 threads.
__global__ void __launch_bounds__(256) k_step1(int t, const float* __restrict__ maskp,
                                               const float* __restrict__ bz2, const float* __restrict__ br2,
                                               const float* __restrict__ bh2,
                                               float* __restrict__ out, float* __restrict__ ws)
{
  __shared__ float s_h[256];
  __shared__ float s_part[3][8][32];
  __shared__ float s_h1[32];
  int tid = threadIdx.x;
  int b = blockIdx.x >> 3, q = blockIdx.x & 7;
  const unsigned pr = (unsigned)((t - 1) & 1);
  const unsigned pw = (unsigned)(t & 1);
  {
    int n = tid;
    float h1v = ws[OFF_H1 + pr*4096u + b*256 + n];
    float gz = ws[OFF_G2CT + pr*12288u + (b*3 + 0)*256 + n];
    float gr = ws[OFF_G2CT + pr*12288u + (b*3 + 1)*256 + n];
    float gc = ws[OFF_G2CT + pr*12288u + (b*3 + 2)*256 + n];
    float gu = 0.f;
    #pragma unroll
    for (int qq = 0; qq < 8; ++qq) {
      gz += ws[OFF_G2HP + pr*98304u + (size_t)((b*8 + qq)*3 + 0)*256 + n];
      gr += ws[OFF_G2HP + pr*98304u + (size_t)((b*8 + qq)*3 + 1)*256 + n];
      gu += ws[OFF_G2HP + pr*98304u + (size_t)((b*8 + qq)*3 + 2)*256 + n];
    }
    float z2 = sigf(gz + bz2[n]);
    float r2 = sigf(gr + br2[n]);
    float h2p = tanhf_(gc + (gu + bh2[n]) * r2);
    float h2 = z2*h1v + (1.f - z2)*h2p;
    float m = maskp[(t-1)*16 + b];
    float hv = m*h2 + (1.f - m)*h1v;
    if (q == 0) out[OUT_H2 + (size_t)((t-1)*16 + b)*256 + n] = hv;
    s_h[n] = hv;
  }
  if (q == 0) {
    for (int i = tid; i < 768; i += 256) ws[OFF_AUN + b*768 + i] = 0.f;
    #pragma unroll
    for (int g = 0; g < 3; ++g) ws[OFF_G2CT + pw*12288u + (b*3 + g)*256 + tid] = 0.f;
  }
  __syncthreads();
  {
    int nl = tid & 31, kq = tid >> 5;
    int col = q*32 + nl;
    const float* Wz = ws + OFF_UHZT;
    const float* Wr = ws + OFF_UHZT + 65536u;
    const float* Wh = ws + OFF_UHZT + 131072u;
    float a0 = 0.f, a1 = 0.f, a2 = 0.f;
    #pragma unroll 8
    for (int k = kq*32; k < kq*32 + 32; ++k) {
      float hk = s_h[k];
      a0 += Wz[k*256 + col]*hk; a1 += Wr[k*256 + col]*hk; a2 += Wh[k*256 + col]*hk;
    }
    s_part[0][kq][nl] = a0; s_part[1][kq][nl] = a1; s_part[2][kq][nl] = a2;
  }
  __syncthreads();
  if (tid < 32) {
    float g0 = 0.f, g1 = 0.f, g2 = 0.f;
    #pragma unroll
    for (int j = 0; j < 8; ++j) { g0 += s_part[0][j][tid]; g1 += s_part[1][j][tid]; g2 += s_part[2][j][tid]; }
    int col = q*32 + tid;
    int ro = (t*16 + b)*256 + col;
    float z1 = sigf(g0 + ws[OFF_SZ + ro]);
    float r1 = sigf(g1 + ws[OFF_SR + ro]);
    float h1p = tanhf_(g2 * r1 + ws[OFF_SH + ro]);
    float m = maskp[t*16 + b];
    float h = s_h[col];
    float h1 = m*(z1*h + (1.f - z1)*h1p) + (1.f - m)*h;
    s_h1[tid] = h1;
    ws[OFF_H1 + pw*4096u + b*256 + col] = h1;
  }
  __syncthreads();
  {
    float acc0 = 0.f, acc1 = 0.f;
    #pragma unroll 8
    for (int j = 0; j < 32; ++j) {
      float h1j = s_h1[j];
      acc0 += ws[OFF_WAT + (q*32 + j)*512 + tid]       * h1j;
      acc1 += ws[OFF_WAT + (q*32 + j)*512 + tid + 256] * h1j;
    }
    ws[OFF_WAHP + (size_t)(b*8 + q)*512 + tid]       = acc0;
    ws[OFF_WAHP + (size_t)(b*8 + q)*512 + tid + 256] = acc1;
  }
  #pragma unroll
  for (int g = 0; g < 3; ++g) {
    const float* Wb = ws + OFF_UHZ2T + g*65536u;
    float acc = 0.f;
    #pragma unroll 8
    for (int j = 0; j < 32; ++j) acc += Wb[(q*32 + j)*256 + tid] * s_h1[j];
    ws[OFF_G2HP + pw*98304u + (size_t)((b*8 + q)*3 + g)*256 + tid] = acc;
  }
}

// ---------------- cover: bf16 MFMA GEMM + tanh + va partial e ----------------
// RESTRUCTURED (R9): grid 768 = b(16) x mt2(24 of 32 rows) x nt2(2 of 256 cols).
// Old grid 384 = 1.5 blocks/CU: second scheduling round ran at 50% machine
// utilization. Half-size blocks at 3/CU distribute evenly. Same MFMA tile math:
// rows = c5 (one 32x32 M-tile), 4 waves x 64-col slices (acc[2]); sWah/sVa load
// only the used 256-col half. e-sum atomic partials regroup 4x128 -> 8x64 cols
// (fp reassociation only).
__global__ void __launch_bounds__(256) k_cover(const float* __restrict__ va,
                                               const float* __restrict__ Uab, const float* __restrict__ Ufb,
                                               float* __restrict__ ws)
{
  __shared__ unsigned short sA[32 * 136];
  __shared__ float sWah[256];
  __shared__ float sVa[256];
  int tid = threadIdx.x;
  int blk = blockIdx.x;
  int b = blk / 48; int rem2 = blk % 48; int mt2 = rem2 >> 1; int nt2 = rem2 & 1;
  {
    int col = nt2*256 + tid;
    float v = Uab[col] + Ufb[col];
    #pragma unroll
    for (int qq = 0; qq < 8; ++qq) v += ws[OFF_WAHP + (size_t)(b*8 + qq)*512 + col];
    sWah[tid] = v; sVa[tid] = va[col];
  }
  const float* ap = ws + OFF_AP + b*768;
  for (int idx = tid; idx < 32*128; idx += 256) {
    int r = idx & 31, k = idx >> 5;
    int hw = mt2*32 + r; int hh = hw / 48; int wwp = hw - hh*48;
    float v = 0.f;
    if (k < 121) {
      int kh = k / 11, kw = k - kh*11;
      int shh = hh + kh - 5, sww = wwp + kw - 5;
      if (shh >= 0 && shh < 16 && sww >= 0 && sww < 48) v = ap[shh*48 + sww];
    }
    sA[r*136 + k] = f2bf(v);
  }
  __syncthreads();
  int lane = tid & 63; int w = tid >> 6;
  int c5 = lane & 31; int q = lane >> 5;
  bf16x8 af[8];
  #pragma unroll
  for (int ks = 0; ks < 8; ++ks)
    af[ks] = *(const bf16x8*)(sA + c5*136 + ks*16 + q*8);
  const unsigned short* kct = (const unsigned short*)(ws + OFF_KCB);
  const unsigned short* uact = (const unsigned short*)(ws + OFF_UACTX);
  int n_base = nt2*256 + w*64;
  floatx16 acc[2];
  #pragma unroll
  for (int r = 0; r < 16; ++r) { acc[0][r] = 0.f; acc[1][r] = 0.f; }
  const bf16x8* kb0 = (const bf16x8*)(kct + (size_t)(n_base + c5)*128 + q*8);
  const bf16x8* kb1 = (const bf16x8*)(kct + (size_t)(n_base + 32 + c5)*128 + q*8);
  #pragma unroll
  for (int ks = 0; ks < 8; ++ks) {
    bf16x8 b0 = kb0[ks*2];
    bf16x8 b1 = kb1[ks*2];
    acc[0] = __builtin_amdgcn_mfma_f32_32x32x16_bf16(af[ks], b0, acc[0], 0, 0, 0);
    acc[1] = __builtin_amdgcn_mfma_f32_32x32x16_bf16(af[ks], b1, acc[1], 0, 0, 0);
  }
  float e_part[16];
  #pragma unroll
  for (int r = 0; r < 16; ++r) e_part[r] = 0.f;
  #pragma unroll
  for (int half = 0; half < 2; ++half) {
    int col = n_base + half*32 + c5;
    int cl = w*64 + half*32 + c5;
    float vav = sVa[cl], wah = sWah[cl];
    #pragma unroll
    for (int r = 0; r < 16; ++r) {
      int row32 = (r & 3) + 8*(r >> 2) + 4*q;
      int hw = mt2*32 + row32;
      float x = acc[half][r] + wah + bfval(uact[((size_t)(b*768 + hw))*512 + col]);
      e_part[r] += vav * tanhf_(x);
    }
  }
  #pragma unroll
  for (int r = 0; r < 16; ++r) {
    float v = e_part[r];
    v += __shfl_xor(v, 1); v += __shfl_xor(v, 2); v += __shfl_xor(v, 4);
    v += __shfl_xor(v, 8); v += __shfl_xor(v, 16);
    e_part[r] = v;
  }
  if (c5 == 0) {
    #pragma unroll
    for (int r = 0; r < 16; ++r) {
      int row32 = (r & 3) + 8*(r >> 2) + 4*q;
      int hw = mt2*32 + row32;
      atomicAdd(&ws[OFF_AUN + b*768 + hw], e_part[r]);
    }
  }
}

// ---------------- alpha: softmax + AP + outputs + ct + Wc.ct -> G2CT[t&1] ----------------
// grid 352 = b(16) x dc(22)
__global__ void __launch_bounds__(256) k_alpha(int t, const float* __restrict__ ctx, const float* __restrict__ cmask,
                                               const float* __restrict__ vab,
                                               float* __restrict__ out, float* __restrict__ ws)
{
  __shared__ __align__(16) float s_al[768];
  __shared__ float s_red[4];
  __shared__ float s_ct[32];
  int tid = threadIdx.x;
  int b = blockIdx.x / 22, dc = blockIdx.x % 22;
  const unsigned pw = (unsigned)(t & 1);
  float vb = vab[0];
  float local = 0.f;
  for (int i = tid; i < 768; i += 256) {
    float e = ws[OFF_AUN + b*768 + i] + vb;
    float un = __expf(e) * cmask[b*768 + i];
    s_al[i] = un; local += un;
  }
  local += __shfl_xor(local, 1); local += __shfl_xor(local, 2); local += __shfl_xor(local, 4);
  local += __shfl_xor(local, 8); local += __shfl_xor(local, 16); local += __shfl_xor(local, 32);
  if ((tid & 63) == 0) s_red[tid >> 6] = local;
  __syncthreads();
  float inv = 1.f / (s_red[0] + s_red[1] + s_red[2] + s_red[3]);
  if (dc == 0) {
    float* outA = out + OUT_AL + (size_t)(t*16 + b)*768;
    float* outP = out + OUT_AP + (size_t)(t*16 + b)*768;
    for (int i = tid; i < 768; i += 256) {
      float av = s_al[i] * inv;
      float np = ws[OFF_AP + b*768 + i] + av;
      ws[OFF_AP + b*768 + i] = np;
      outA[i] = av; outP[i] = np;
    }
  }
  {
    int dl = tid >> 3, qq = tid & 7;
    int d = dc*32 + dl;
    if (d < 684) {
      const float4* cp  = (const float4*)(ctx + ((size_t)(b*684 + d))*768);
      const float4* alp = (const float4*)s_al;
      float s = 0.f;
      #pragma unroll 8
      for (int i = 0; i < 24; ++i) {
        float4 cv = cp[i*8 + qq]; float4 av = alp[i*8 + qq];
        s += cv.x*av.x + cv.y*av.y + cv.z*av.z + cv.w*av.w;
      }
      s += __shfl_xor(s, 1); s += __shfl_xor(s, 2); s += __shfl_xor(s, 4);
      s *= inv;
      if (qq == 0) {
        out[OUT_CT + (size_t)(t*16 + b)*684 + d] = s;
        s_ct[dl] = s;
      }
    } else if (qq == 0) {
      s_ct[dl] = 0.f;
    }
  }
  __syncthreads();
  {
    int d0 = dc*32;
    int jm = 684 - d0; if (jm > 32) jm = 32;
    #pragma unroll
    for (int g = 0; g < 3; ++g) {
      const float* Wb = ws + OFF_WCZT + g*175104u;
      float acc = 0.f;
      for (int j = 0; j < jm; ++j) acc += Wb[(d0 + j)*256 + tid] * s_ct[j];
      atomicAdd(&ws[OFF_G2CT + pw*12288u + (size_t)(b*3 + g)*256 + tid], acc);
    }
  }
}

// ---------------- final combine for t=47 ----------------
__global__ void k_final(const float* __restrict__ maskp, const float* __restrict__ bz2,
                        const float* __restrict__ br2, const float* __restrict__ bh2,
                        float* __restrict__ out, float* __restrict__ ws)
{
  int b = blockIdx.x, n = threadIdx.x;
  const unsigned pr = 1u;  // 47 & 1
  float h1v = ws[OFF_H1 + pr*4096u + b*256 + n];
  float gz = ws[OFF_G2CT + pr*12288u + (b*3 + 0)*256 + n];
  float gr = ws[OFF_G2CT + pr*12288u + (b*3 + 1)*256 + n];
  float gc = ws[OFF_G2CT + pr*12288u + (b*3 + 2)*256 + n];
  float gu = 0.f;
  #pragma unroll
  for (int qq = 0; qq < 8; ++qq) {
    gz += ws[OFF_G2HP + pr*98304u + (size_t)((b*8 + qq)*3 + 0)*256 + n];
    gr += ws[OFF_G2HP + pr*98304u + (size_t)((b*8 + qq)*3 + 1)*256 + n];
    gu += ws[OFF_G2HP + pr*98304u + (size_t)((b*8 + qq)*3 + 2)*256 + n];
  }
  float z2 = sigf(gz + bz2[n]);
  float r2 = sigf(gr + br2[n]);
  float h2p = tanhf_(gc + (gu + bh2[n]) * r2);
  float h2 = z2*h1v + (1.f - z2)*h2p;
  float m = maskp[47*16 + b];
  out[OUT_H2 + (size_t)(47*16 + b)*256 + n] = m*h2 + (1.f - m)*h1v;
}

extern "C" void kernel_launch(void* const* d_in, const int* in_sizes, int n_in,
                              void* d_out, int out_size, void* d_ws, size_t ws_size,
                              hipStream_t stream)
{
  const float* emb   = (const float*)d_in[0];
  const float* maskp = (const float*)d_in[1];
  const float* ctx   = (const float*)d_in[2];
  const float* cmask = (const float*)d_in[3];
  const float* inits = (const float*)d_in[4];
  const float* Ua    = (const float*)d_in[5];
  const float* Uab   = (const float*)d_in[6];
  const float* Wa    = (const float*)d_in[7];
  const float* Qw    = (const float*)d_in[8];
  const float* Uf    = (const float*)d_in[9];
  const float* Ufb   = (const float*)d_in[10];
  const float* va    = (const float*)d_in[11];
  const float* vab   = (const float*)d_in[12];
  const float* Wyz   = (const float*)d_in[13];
  const float* Wyzb  = (const float*)d_in[14];
  const float* Wyr   = (const float*)d_in[15];
  const float* Wyrb  = (const float*)d_in[16];
  const float* Wyh   = (const float*)d_in[17];
  const float* Wyhb  = (const float*)d_in[18];
  const float* Uhz   = (const float*)d_in[19];
  const float* Uhr   = (const float*)d_in[20];
  const float* Uhh   = (const float*)d_in[21];
  const float* Wcz   = (const float*)d_in[22];
  const float* Wcr   = (const float*)d_in[23];
  const float* Wch   = (const float*)d_in[24];
  const float* Uhz2  = (const float*)d_in[25];
  const float* Uhz2b = (const float*)d_in[26];
  const float* Uhr2  = (const float*)d_in[27];
  const float* Uhr2b = (const float*)d_in[28];
  const float* Uhh2  = (const float*)d_in[29];
  const float* Uhh2b = (const float*)d_in[30];
  float* out = (float*)d_out;
  float* ws  = (float*)d_ws;

  k_prep<<<dim3(6292), dim3(256), 0, stream>>>(Uhz, Uhr, Uhh, Uhz2, Uhr2, Uhh2,
                                               Wyz, Wyr, Wyh, Wa, Wcz, Wcr, Wch, Ua, ws);
  k_kcomb<<<dim3(256), dim3(256), 0, stream>>>(Uf, Qw, ws);
  k_embproj<<<dim3(384), dim3(256), 0, stream>>>(emb, Wyzb, Wyrb, Wyhb, ws);
  k_uactx<<<dim3(768), dim3(256), 0, stream>>>(ctx, ws);
  k_step0<<<dim3(128), dim3(256), 0, stream>>>(inits, maskp, ws);

  k_cover<<<dim3(768), dim3(256), 0, stream>>>(va, Uab, Ufb, ws);
  k_alpha<<<dim3(352), dim3(256), 0, stream>>>(0, ctx, cmask, vab, out, ws);
  for (int t = 1; t < 48; ++t) {
    k_step1<<<dim3(128), dim3(256), 0, stream>>>(t, maskp, Uhz2b, Uhr2b, Uhh2b, out, ws);
    k_cover<<<dim3(768), dim3(256), 0, stream>>>(va, Uab, Ufb, ws);
    k_alpha<<<dim3(352), dim3(256), 0, stream>>>(t, ctx, cmask, vab, out, ws);
  }
  k_final<<<dim3(16), dim3(256), 0, stream>>>(maskp, Uhz2b, Uhr2b, Uhh2b, out, ws);
  (void)in_sizes; (void)n_in; (void)out_size; (void)ws_size;
}

// Round 11
// 2208.589 us; speedup vs baseline: 1.1534x; 1.0079x over previous
//
#include <hip/hip_runtime.h>
#include <hip/hip_bf16.h>
#include <stdint.h>

// Problem dims
#define T_  48
#define B_  16
#define HW_ 768
#define D_  684
#define N_  256
#define A_  512

// Workspace layout (float offsets). Footprint <= proven 5445312 floats.
#define OFF_SZ     0u
#define OFF_SR     196608u
#define OFF_SH     393216u
#define OFF_UHZT   589824u    // gates1 weights [k][n] x3 (196608)
#define OFF_UHZ2T  786432u    // gates2 h-weights [k][n] x3 (196608)
#define OFF_G2HP   983040u    // DOUBLE-BUF Uh2.h1 partials [2][b][8][3][256] = 196608 -> 1179648
#define OFF_WAT    1179648u   // [k=256][a=512] (131072) -> 1310720
#define OFF_WCZT   1310720u   // [d=684][n=256] x3 (525312) -> 1836032
#define OFF_UAB    1836032u   // Ua bf16 [a=512][k=688] = 176128 -> 2012160
#define OFF_WAHP   2012160u   // Wa.h1 partials [b][8][512] = 65536 -> 2077696
#define OFF_H1     2077696u   // DOUBLE-BUF h1 [2][b][256] = 8192 -> 2085888
#define OFF_KCB    2186240u   // K_comb^T bf16 [a=512][k=128] = 32768 -> 2219008
#define OFF_G2CT   2219008u   // DOUBLE-BUF Wc.ct accum [2][b][3][256] = 24576 -> 2243584
#define OFF_AP     2275008u   // alpha_past B*HW (12288)
#define OFF_AUN    2287296u   // per-step e sums (atomic) B*HW (12288)
#define OFF_UACTX  2299584u   // Ua_ctx bf16 [b][hw][a]; end 5445312

// d_out offsets
#define OUT_H2 0u
#define OUT_CT 196608u
#define OUT_AL 721920u
#define OUT_AP 1311744u

typedef __attribute__((ext_vector_type(8))) short bf16x8;
typedef __attribute__((ext_vector_type(16))) float floatx16;

__device__ __forceinline__ float sigf(float x)  { return 1.f / (1.f + __expf(-x)); }
__device__ __forceinline__ float tanhf_(float x){ float e = __expf(2.f*x); return 1.f - 2.f/(e + 1.f); }
__device__ __forceinline__ float bfval(unsigned short u){ return __uint_as_float(((unsigned)u) << 16); }
__device__ __forceinline__ unsigned short f2bf(float f){
  unsigned int x = __float_as_uint(f);
  return (unsigned short)((x + 0x7fffu + ((x >> 16) & 1u)) >> 16);  // RNE
}

// ---------------- prep: weight transposes + Ua->bf16 + zero alpha_past ----------------
__global__ void k_prep(const float* __restrict__ Uhz, const float* __restrict__ Uhr, const float* __restrict__ Uhh,
                       const float* __restrict__ Uhz2, const float* __restrict__ Uhr2, const float* __restrict__ Uhh2,
                       const float* __restrict__ Wyz, const float* __restrict__ Wyr, const float* __restrict__ Wyh,
                       const float* __restrict__ Wa, const float* __restrict__ Wcz, const float* __restrict__ Wcr,
                       const float* __restrict__ Wch, const float* __restrict__ Ua, float* __restrict__ ws)
{
  int i = blockIdx.x * 256 + threadIdx.x;
  if (i < 589824) {                     // 9 x (256x256) -> [k][n]
    int m = i >> 16, rem = i & 65535, r = rem >> 8, c = rem & 255;
    const float* s;
    unsigned dst;
    switch (m) { case 0: s=Uhz;  dst=OFF_UHZT;           break;
                 case 1: s=Uhr;  dst=OFF_UHZT+65536u;    break;
                 case 2: s=Uhh;  dst=OFF_UHZT+131072u;   break;
                 case 3: s=Uhz2; dst=OFF_UHZ2T;          break;
                 case 4: s=Uhr2; dst=OFF_UHZ2T+65536u;   break;
                 case 5: s=Uhh2; dst=OFF_UHZ2T+131072u;  break;
                 case 6: s=Wyz;  dst=983040u;            break;  // scratch (embproj)
                 case 7: s=Wyr;  dst=1048576u;           break;
                 default: s=Wyh; dst=1114112u;           break;}
    ws[dst + c*256 + r] = s[rem];
  } else if (i < 720896) {              // Wa [512][256] -> WaT [256][512]
    int j = i - 589824, r = j >> 8, c = j & 255;
    ws[OFF_WAT + c*512 + r] = Wa[j];
  } else if (i < 1246208) {             // Wc* [256][684] -> [684][256]
    int j = i - 720896; int m = j / 175104; int rem = j - m*175104;
    int r = rem / 684, c = rem - r*684;
    const float* s = (m == 0) ? Wcz : (m == 1) ? Wcr : Wch;
    ws[OFF_WCZT + m*175104 + c*256 + r] = s[rem];
  } else if (i < 1596416) {             // Ua [512][684] fp32 -> bf16 [a][688]
    int j = i - 1246208; int a = j / 684, d = j - a*684;
    unsigned short* uab = (unsigned short*)(ws + OFF_UAB);
    uab[(size_t)a*688 + d] = f2bf(Ua[j]);
  } else if (i < 1598464) {             // UaB k-padding zeros
    int j = i - 1596416; int a = j >> 2, d = 684 + (j & 3);
    unsigned short* uab = (unsigned short*)(ws + OFF_UAB);
    uab[(size_t)a*688 + d] = 0;
  } else if (i < 1610752) {             // zero alpha_past
    ws[OFF_AP + (i - 1598464)] = 0.f;
  }
}

// ---------------- K_comb bf16 [a=512][k=128] ----------------
// (R1): one thread per output element; 256 blocks, coalesced Qw, fp32 acc.
__global__ void __launch_bounds__(256) k_kcomb(const float* __restrict__ Uf, const float* __restrict__ Qw,
                                               float* __restrict__ ws)
{
  unsigned short* kcb = (unsigned short*)(ws + OFF_KCB);
  int tid = threadIdx.x;
  int k = tid & 127, rr = tid >> 7;
  int a = blockIdx.x * 2 + rr;
  if (k >= 121) { kcb[(size_t)a*128 + k] = 0; return; }
  const float* uf = Uf + (size_t)a*512;
  float acc = 0.f;
  #pragma unroll 8
  for (int c = 0; c < 512; ++c) acc += uf[c] * Qw[c*121 + k];
  kcb[(size_t)a*128 + k] = f2bf(acc);
}

// ---------------- embedding projections ----------------
// (R3): grid 384 = rowchunk(48 of 16) x colchunk(8 of 32); block-internal 8-way k-split.
__global__ void __launch_bounds__(256) k_embproj(const float* __restrict__ emb, const float* __restrict__ bz,
                                                 const float* __restrict__ br, const float* __restrict__ bh,
                                                 float* __restrict__ ws)
{
  __shared__ __align__(16) float s_e[256 * 16];      // [m][r] 16 KB
  __shared__ float s_part[8][32][48];                // [kg][col][g*16+r] 48 KB
  int tid = threadIdx.x;
  int rc = blockIdx.x >> 3, cc = blockIdx.x & 7;
  int row0 = rc * 16, n0 = cc * 32;
  for (int i = tid; i < 4096; i += 256) { int r = i >> 8, m = i & 255; s_e[m*16 + r] = emb[(row0 + r)*256 + m]; }
  __syncthreads();
  int col = tid & 31, kg = tid >> 5;
  int n = n0 + col;
  float az[16], ar[16], ah[16];
  #pragma unroll
  for (int r = 0; r < 16; ++r) { az[r] = 0.f; ar[r] = 0.f; ah[r] = 0.f; }
  #pragma unroll 4
  for (int m = kg*32; m < kg*32 + 32; ++m) {
    float wz = ws[983040u + m*256 + n];
    float wr = ws[1048576u + m*256 + n];
    float wh = ws[1114112u + m*256 + n];
    const float4* ep = (const float4*)(s_e + m*16);
    #pragma unroll
    for (int rq = 0; rq < 4; ++rq) {
      float4 e4 = ep[rq];
      az[rq*4+0] += wz*e4.x; az[rq*4+1] += wz*e4.y; az[rq*4+2] += wz*e4.z; az[rq*4+3] += wz*e4.w;
      ar[rq*4+0] += wr*e4.x; ar[rq*4+1] += wr*e4.y; ar[rq*4+2] += wr*e4.z; ar[rq*4+3] += wr*e4.w;
      ah[rq*4+0] += wh*e4.x; ah[rq*4+1] += wh*e4.y; ah[rq*4+2] += wh*e4.z; ah[rq*4+3] += wh*e4.w;
    }
  }
  #pragma unroll
  for (int r = 0; r < 16; ++r) {
    s_part[kg][col][r]      = az[r];
    s_part[kg][col][16 + r] = ar[r];
    s_part[kg][col][32 + r] = ah[r];
  }
  __syncthreads();
  {
    int rcol = tid & 31, j0 = (tid >> 5) * 6;
    int rn = n0 + rcol;
    #pragma unroll
    for (int jj = 0; jj < 6; ++jj) {
      int j = j0 + jj;
      float v = 0.f;
      #pragma unroll
      for (int k8 = 0; k8 < 8; ++k8) v += s_part[k8][rcol][j];
      int g = j >> 4, r = j & 15;
      const float* bp = (g == 0) ? bz : (g == 1) ? br : bh;
      v += bp[rn];
      ws[g*196608u + (row0 + r)*256 + rn] = v;
    }
  }
}

// ---------------- Ua_ctx via bf16 MFMA ----------------
// (R6): grid 768, ah-MAJOR block order + 1-deep software prefetch.
__global__ void __launch_bounds__(256) k_uactx(const float* __restrict__ ctx, float* __restrict__ ws)
{
  int tid = threadIdx.x;
  int blk = blockIdx.x;
  int ah = blk / 384; int rem = blk % 384; int b = rem / 24; int ch = rem % 24;
  int hw0 = ch * 32;
  const unsigned short* uab = (const unsigned short*)(ws + OFF_UAB);
  int lane = tid & 63, w = tid >> 6;
  int c5 = lane & 31, q = lane >> 5;
  int nb = ah*256 + w*64;
  const float* cbase = ctx + (size_t)b*684*768 + hw0 + c5;   // + d*768
  floatx16 acc[2];
  #pragma unroll
  for (int nt = 0; nt < 2; ++nt)
    #pragma unroll
    for (int r = 0; r < 16; ++r) acc[nt][r] = 0.f;
  // prefetch kt=0 (d = q*8+e <= 15 < 684, no guard)
  float av[8];
  #pragma unroll
  for (int e = 0; e < 8; ++e) av[e] = cbase[(size_t)(q*8 + e)*768];
  for (int kt = 0; kt < 43; ++kt) {
    bf16x8 af;
    #pragma unroll
    for (int e = 0; e < 8; ++e) af[e] = (short)f2bf(av[e]);
    if (kt < 42) {                       // prefetch kt+1 during MFMAs
      int d0 = (kt + 1)*16 + q*8;
      #pragma unroll
      for (int e = 0; e < 8; ++e) {
        int d = d0 + e;
        av[e] = (d < 684) ? cbase[(size_t)d*768] : 0.f;
      }
    }
    #pragma unroll
    for (int nt = 0; nt < 2; ++nt) {
      bf16x8 bf = *(const bf16x8*)(uab + (size_t)(nb + nt*32 + c5)*688 + kt*16 + q*8);
      acc[nt] = __builtin_amdgcn_mfma_f32_32x32x16_bf16(af, bf, acc[nt], 0, 0, 0);
    }
  }
  unsigned short* up = (unsigned short*)(ws + OFF_UACTX);
  #pragma unroll
  for (int nt = 0; nt < 2; ++nt) {
    int col = nb + nt*32 + c5;
    #pragma unroll
    for (int r = 0; r < 16; ++r) {
      int row32 = (r & 3) + 8*(r >> 2) + 4*q;
      int hw = hw0 + row32;
      up[((size_t)(b*768 + hw))*512 + col] = f2bf(acc[nt][r]);
    }
  }
}

// ---------------- step0: h1(0) -> H1[0], WAHP/G2HP[0] partials, zero AUN/G2CT[0] ----------------
// (R0): grid 128 = b(16) x q(8).
__global__ void __launch_bounds__(256) k_step0(const float* __restrict__ inits, const float* __restrict__ maskp,
                                               float* __restrict__ ws)
{
  __shared__ float s_h[256];
  __shared__ float s_part[3][8][32];
  __shared__ float s_h1[32];
  int tid = threadIdx.x;
  int b = blockIdx.x >> 3, q = blockIdx.x & 7;
  s_h[tid] = inits[b*256 + tid];
  if (q == 0) {
    for (int i = tid; i < 768; i += 256) ws[OFF_AUN + b*768 + i] = 0.f;
    #pragma unroll
    for (int g = 0; g < 3; ++g) ws[OFF_G2CT + (b*3 + g)*256 + tid] = 0.f;   // buf 0
  }
  __syncthreads();
  {
    int nl = tid & 31, kq = tid >> 5;
    int col = q*32 + nl;
    const float* Wz = ws + OFF_UHZT;
    const float* Wr = ws + OFF_UHZT + 65536u;
    const float* Wh = ws + OFF_UHZT + 131072u;
    float a0 = 0.f, a1 = 0.f, a2 = 0.f;
    #pragma unroll 8
    for (int k = kq*32; k < kq*32 + 32; ++k) {
      float hk = s_h[k];
      a0 += Wz[k*256 + col]*hk; a1 += Wr[k*256 + col]*hk; a2 += Wh[k*256 + col]*hk;
    }
    s_part[0][kq][nl] = a0; s_part[1][kq][nl] = a1; s_part[2][kq][nl] = a2;
  }
  __syncthreads();
  if (tid < 32) {
    float g0 = 0.f, g1 = 0.f, g2 = 0.f;
    #pragma unroll
    for (int j = 0; j < 8; ++j) { g0 += s_part[0][j][tid]; g1 += s_part[1][j][tid]; g2 += s_part[2][j][tid]; }
    int col = q*32 + tid;
    int ro = b*256 + col;                 // t = 0
    float z1 = sigf(g0 + ws[OFF_SZ + ro]);
    float r1 = sigf(g1 + ws[OFF_SR + ro]);
    float h1p = tanhf_(g2 * r1 + ws[OFF_SH + ro]);
    float m = maskp[b];                   // t = 0
    float h = s_h[col];
    float h1 = m*(z1*h + (1.f - z1)*h1p) + (1.f - m)*h;
    s_h1[tid] = h1;
    ws[OFF_H1 + b*256 + col] = h1;        // buf 0
  }
  __syncthreads();
  {
    float acc0 = 0.f, acc1 = 0.f;
    #pragma unroll 8
    for (int j = 0; j < 32; ++j) {
      float h1j = s_h1[j];
      acc0 += ws[OFF_WAT + (q*32 + j)*512 + tid]       * h1j;
      acc1 += ws[OFF_WAT + (q*32 + j)*512 + tid + 256] * h1j;
    }
    ws[OFF_WAHP + (size_t)(b*8 + q)*512 + tid]       = acc0;
    ws[OFF_WAHP + (size_t)(b*8 + q)*512 + tid + 256] = acc1;
  }
  #pragma unroll
  for (int g = 0; g < 3; ++g) {
    const float* Wb = ws + OFF_UHZ2T + g*65536u;
    float acc = 0.f;
    #pragma unroll 8
    for (int j = 0; j < 32; ++j) acc += Wb[(q*32 + j)*256 + tid] * s_h1[j];
    ws[OFF_G2HP + (size_t)((b*8 + q)*3 + g)*256 + tid] = acc;   // buf 0
  }
}

// ---------------- step1(t>=1): h2(t-1) combine + gates1(t) + h1(t) + partials ----------------
// (R6): grid 128 = b(16) x q(8), 256 threads.
__global__ void __launch_bounds__(256) k_step1(int t, const float* __restrict__ maskp,
                                               const float* __restrict__ bz2, const float* __restrict__ br2,
                                               const float* __restrict__ bh2,
                                               float* __restrict__ out, float* __restrict__ ws)
{
  __shared__ float s_h[256];
  __shared__ float s_part[3][8][32];
  __shared__ float s_h1[32];
  int tid = threadIdx.x;
  int b = blockIdx.x >> 3, q = blockIdx.x & 7;
  const unsigned pr = (unsigned)((t - 1) & 1);
  const unsigned pw = (unsigned)(t & 1);
  {
    int n = tid;
    float h1v = ws[OFF_H1 + pr*4096u + b*256 + n];
    float gz = ws[OFF_G2CT + pr*12288u + (b*3 + 0)*256 + n];
    float gr = ws[OFF_G2CT + pr*12288u + (b*3 + 1)*256 + n];
    float gc = ws[OFF_G2CT + pr*12288u + (b*3 + 2)*256 + n];
    float gu = 0.f;
    #pragma unroll
    for (int qq = 0; qq < 8; ++qq) {
      gz += ws[OFF_G2HP + pr*98304u + (size_t)((b*8 + qq)*3 + 0)*256 + n];
      gr += ws[OFF_G2HP + pr*98304u + (size_t)((b*8 + qq)*3 + 1)*256 + n];
      gu += ws[OFF_G2HP + pr*98304u + (size_t)((b*8 + qq)*3 + 2)*256 + n];
    }
    float z2 = sigf(gz + bz2[n]);
    float r2 = sigf(gr + br2[n]);
    float h2p = tanhf_(gc + (gu + bh2[n]) * r2);
    float h2 = z2*h1v + (1.f - z2)*h2p;
    float m = maskp[(t-1)*16 + b];
    float hv = m*h2 + (1.f - m)*h1v;
    if (q == 0) out[OUT_H2 + (size_t)((t-1)*16 + b)*256 + n] = hv;
    s_h[n] = hv;
  }
  if (q == 0) {
    for (int i = tid; i < 768; i += 256) ws[OFF_AUN + b*768 + i] = 0.f;
    #pragma unroll
    for (int g = 0; g < 3; ++g) ws[OFF_G2CT + pw*12288u + (b*3 + g)*256 + tid] = 0.f;
  }
  __syncthreads();
  {
    int nl = tid & 31, kq = tid >> 5;
    int col = q*32 + nl;
    const float* Wz = ws + OFF_UHZT;
    const float* Wr = ws + OFF_UHZT + 65536u;
    const float* Wh = ws + OFF_UHZT + 131072u;
    float a0 = 0.f, a1 = 0.f, a2 = 0.f;
    #pragma unroll 8
    for (int k = kq*32; k < kq*32 + 32; ++k) {
      float hk = s_h[k];
      a0 += Wz[k*256 + col]*hk; a1 += Wr[k*256 + col]*hk; a2 += Wh[k*256 + col]*hk;
    }
    s_part[0][kq][nl] = a0; s_part[1][kq][nl] = a1; s_part[2][kq][nl] = a2;
  }
  __syncthreads();
  if (tid < 32) {
    float g0 = 0.f, g1 = 0.f, g2 = 0.f;
    #pragma unroll
    for (int j = 0; j < 8; ++j) { g0 += s_part[0][j][tid]; g1 += s_part[1][j][tid]; g2 += s_part[2][j][tid]; }
    int col = q*32 + tid;
    int ro = (t*16 + b)*256 + col;
    float z1 = sigf(g0 + ws[OFF_SZ + ro]);
    float r1 = sigf(g1 + ws[OFF_SR + ro]);
    float h1p = tanhf_(g2 * r1 + ws[OFF_SH + ro]);
    float m = maskp[t*16 + b];
    float h = s_h[col];
    float h1 = m*(z1*h + (1.f - z1)*h1p) + (1.f - m)*h;
    s_h1[tid] = h1;
    ws[OFF_H1 + pw*4096u + b*256 + col] = h1;
  }
  __syncthreads();
  {
    float acc0 = 0.f, acc1 = 0.f;
    #pragma unroll 8
    for (int j = 0; j < 32; ++j) {
      float h1j = s_h1[j];
      acc0 += ws[OFF_WAT + (q*32 + j)*512 + tid]       * h1j;
      acc1 += ws[OFF_WAT + (q*32 + j)*512 + tid + 256] * h1j;
    }
    ws[OFF_WAHP + (size_t)(b*8 + q)*512 + tid]       = acc0;
    ws[OFF_WAHP + (size_t)(b*8 + q)*512 + tid + 256] = acc1;
  }
  #pragma unroll
  for (int g = 0; g < 3; ++g) {
    const float* Wb = ws + OFF_UHZ2T + g*65536u;
    float acc = 0.f;
    #pragma unroll 8
    for (int j = 0; j < 32; ++j) acc += Wb[(q*32 + j)*256 + tid] * s_h1[j];
    ws[OFF_G2HP + pw*98304u + (size_t)((b*8 + q)*3 + g)*256 + tid] = acc;
  }
}

// ---------------- cover: bf16 MFMA GEMM + tanh + va partial e ----------------
// (R9): grid 768 = b(16) x mt2(24 of 32 rows) x nt2(2 of 256 cols).
__global__ void __launch_bounds__(256) k_cover(const float* __restrict__ va,
                                               const float* __restrict__ Uab, const float* __restrict__ Ufb,
                                               float* __restrict__ ws)
{
  __shared__ unsigned short sA[32 * 136];
  __shared__ float sWah[256];
  __shared__ float sVa[256];
  int tid = threadIdx.x;
  int blk = blockIdx.x;
  int b = blk / 48; int rem2 = blk % 48; int mt2 = rem2 >> 1; int nt2 = rem2 & 1;
  {
    int col = nt2*256 + tid;
    float v = Uab[col] + Ufb[col];
    #pragma unroll
    for (int qq = 0; qq < 8; ++qq) v += ws[OFF_WAHP + (size_t)(b*8 + qq)*512 + col];
    sWah[tid] = v; sVa[tid] = va[col];
  }
  const float* ap = ws + OFF_AP + b*768;
  for (int idx = tid; idx < 32*128; idx += 256) {
    int r = idx & 31, k = idx >> 5;
    int hw = mt2*32 + r; int hh = hw / 48; int wwp = hw - hh*48;
    float v = 0.f;
    if (k < 121) {
      int kh = k / 11, kw = k - kh*11;
      int shh = hh + kh - 5, sww = wwp + kw - 5;
      if (shh >= 0 && shh < 16 && sww >= 0 && sww < 48) v = ap[shh*48 + sww];
    }
    sA[r*136 + k] = f2bf(v);
  }
  __syncthreads();
  int lane = tid & 63; int w = tid >> 6;
  int c5 = lane & 31; int q = lane >> 5;
  bf16x8 af[8];
  #pragma unroll
  for (int ks = 0; ks < 8; ++ks)
    af[ks] = *(const bf16x8*)(sA + c5*136 + ks*16 + q*8);
  const unsigned short* kct = (const unsigned short*)(ws + OFF_KCB);
  const unsigned short* uact = (const unsigned short*)(ws + OFF_UACTX);
  int n_base = nt2*256 + w*64;
  floatx16 acc[2];
  #pragma unroll
  for (int r = 0; r < 16; ++r) { acc[0][r] = 0.f; acc[1][r] = 0.f; }
  const bf16x8* kb0 = (const bf16x8*)(kct + (size_t)(n_base + c5)*128 + q*8);
  const bf16x8* kb1 = (const bf16x8*)(kct + (size_t)(n_base + 32 + c5)*128 + q*8);
  #pragma unroll
  for (int ks = 0; ks < 8; ++ks) {
    bf16x8 b0 = kb0[ks*2];
    bf16x8 b1 = kb1[ks*2];
    acc[0] = __builtin_amdgcn_mfma_f32_32x32x16_bf16(af[ks], b0, acc[0], 0, 0, 0);
    acc[1] = __builtin_amdgcn_mfma_f32_32x32x16_bf16(af[ks], b1, acc[1], 0, 0, 0);
  }
  float e_part[16];
  #pragma unroll
  for (int r = 0; r < 16; ++r) e_part[r] = 0.f;
  #pragma unroll
  for (int half = 0; half < 2; ++half) {
    int col = n_base + half*32 + c5;
    int cl = w*64 + half*32 + c5;
    float vav = sVa[cl], wah = sWah[cl];
    #pragma unroll
    for (int r = 0; r < 16; ++r) {
      int row32 = (r & 3) + 8*(r >> 2) + 4*q;
      int hw = mt2*32 + row32;
      float x = acc[half][r] + wah + bfval(uact[((size_t)(b*768 + hw))*512 + col]);
      e_part[r] += vav * tanhf_(x);
    }
  }
  #pragma unroll
  for (int r = 0; r < 16; ++r) {
    float v = e_part[r];
    v += __shfl_xor(v, 1); v += __shfl_xor(v, 2); v += __shfl_xor(v, 4);
    v += __shfl_xor(v, 8); v += __shfl_xor(v, 16);
    e_part[r] = v;
  }
  if (c5 == 0) {
    #pragma unroll
    for (int r = 0; r < 16; ++r) {
      int row32 = (r & 3) + 8*(r >> 2) + 4*q;
      int hw = mt2*32 + row32;
      atomicAdd(&ws[OFF_AUN + b*768 + hw], e_part[r]);
    }
  }
}

// ---------------- alpha: softmax + AP + outputs + ct + Wc.ct -> G2CT[t&1] ----------------
// RESTRUCTURED (R10): grid 688 = b(16) x dc(43 chunks of 16 dims). Old 352-block
// version (32 dims/block, 8 lanes/dim) had ~2x the per-block serial path; these
// small loop kernels are latency-bound (wall time ~ slowest block, R9 lesson).
// Now 16 lanes/dim (12 float4 dot iters) and Wc loop <=16 j-iters. Softmax part
// duplicated ~2x (cheap); G2CT atomic count ~2x (L2, ~us aggregate). ct dot
// reassociates (16-lane tree vs 8-lane) - tolerance-class only.
__global__ void __launch_bounds__(256) k_alpha(int t, const float* __restrict__ ctx, const float* __restrict__ cmask,
                                               const float* __restrict__ vab,
                                               float* __restrict__ out, float* __restrict__ ws)
{
  __shared__ __align__(16) float s_al[768];
  __shared__ float s_red[4];
  __shared__ float s_ct[16];
  int tid = threadIdx.x;
  int b = blockIdx.x / 43, dc = blockIdx.x % 43;
  const unsigned pw = (unsigned)(t & 1);
  float vb = vab[0];
  float local = 0.f;
  for (int i = tid; i < 768; i += 256) {
    float e = ws[OFF_AUN + b*768 + i] + vb;
    float un = __expf(e) * cmask[b*768 + i];
    s_al[i] = un; local += un;
  }
  local += __shfl_xor(local, 1); local += __shfl_xor(local, 2); local += __shfl_xor(local, 4);
  local += __shfl_xor(local, 8); local += __shfl_xor(local, 16); local += __shfl_xor(local, 32);
  if ((tid & 63) == 0) s_red[tid >> 6] = local;
  __syncthreads();
  float inv = 1.f / (s_red[0] + s_red[1] + s_red[2] + s_red[3]);
  if (dc == 0) {
    float* outA = out + OUT_AL + (size_t)(t*16 + b)*768;
    float* outP = out + OUT_AP + (size_t)(t*16 + b)*768;
    for (int i = tid; i < 768; i += 256) {
      float av = s_al[i] * inv;
      float np = ws[OFF_AP + b*768 + i] + av;
      ws[OFF_AP + b*768 + i] = np;
      outA[i] = av; outP[i] = np;
    }
  }
  {
    int dl = tid >> 4, qq = tid & 15;
    int d = dc*16 + dl;
    if (d < 684) {
      const float4* cp  = (const float4*)(ctx + ((size_t)(b*684 + d))*768);
      const float4* alp = (const float4*)s_al;
      float s = 0.f;
      #pragma unroll
      for (int i = 0; i < 12; ++i) {
        float4 cv = cp[i*16 + qq]; float4 av = alp[i*16 + qq];
        s += cv.x*av.x + cv.y*av.y + cv.z*av.z + cv.w*av.w;
      }
      s += __shfl_xor(s, 1); s += __shfl_xor(s, 2); s += __shfl_xor(s, 4); s += __shfl_xor(s, 8);
      s *= inv;
      if (qq == 0) {
        out[OUT_CT + (size_t)(t*16 + b)*684 + d] = s;
        s_ct[dl] = s;
      }
    } else if (qq == 0) {
      s_ct[dl] = 0.f;
    }
  }
  __syncthreads();
  {
    int d0 = dc*16;
    int jm = 684 - d0; if (jm > 16) jm = 16;
    #pragma unroll
    for (int g = 0; g < 3; ++g) {
      const float* Wb = ws + OFF_WCZT + g*175104u;
      float acc = 0.f;
      for (int j = 0; j < jm; ++j) acc += Wb[(d0 + j)*256 + tid] * s_ct[j];
      atomicAdd(&ws[OFF_G2CT + pw*12288u + (size_t)(b*3 + g)*256 + tid], acc);
    }
  }
}

// ---------------- final combine for t=47 ----------------
__global__ void k_final(const float* __restrict__ maskp, const float* __restrict__ bz2,
                        const float* __restrict__ br2, const float* __restrict__ bh2,
                        float* __restrict__ out, float* __restrict__ ws)
{
  int b = blockIdx.x, n = threadIdx.x;
  const unsigned pr = 1u;  // 47 & 1
  float h1v = ws[OFF_H1 + pr*4096u + b*256 + n];
  float gz = ws[OFF_G2CT + pr*12288u + (b*3 + 0)*256 + n];
  float gr = ws[OFF_G2CT + pr*12288u + (b*3 + 1)*256 + n];
  float gc = ws[OFF_G2CT + pr*12288u + (b*3 + 2)*256 + n];
  float gu = 0.f;
  #pragma unroll
  for (int qq = 0; qq < 8; ++qq) {
    gz += ws[OFF_G2HP + pr*98304u + (size_t)((b*8 + qq)*3 + 0)*256 + n];
    gr += ws[OFF_G2HP + pr*98304u + (size_t)((b*8 + qq)*3 + 1)*256 + n];
    gu += ws[OFF_G2HP + pr*98304u + (size_t)((b*8 + qq)*3 + 2)*256 + n];
  }
  float z2 = sigf(gz + bz2[n]);
  float r2 = sigf(gr + br2[n]);
  float h2p = tanhf_(gc + (gu + bh2[n]) * r2);
  float h2 = z2*h1v + (1.f - z2)*h2p;
  float m = maskp[47*16 + b];
  out[OUT_H2 + (size_t)(47*16 + b)*256 + n] = m*h2 + (1.f - m)*h1v;
}

extern "C" void kernel_launch(void* const* d_in, const int* in_sizes, int n_in,
                              void* d_out, int out_size, void* d_ws, size_t ws_size,
                              hipStream_t stream)
{
  const float* emb   = (const float*)d_in[0];
  const float* maskp = (const float*)d_in[1];
  const float* ctx   = (const float*)d_in[2];
  const float* cmask = (const float*)d_in[3];
  const float* inits = (const float*)d_in[4];
  const float* Ua    = (const float*)d_in[5];
  const float* Uab   = (const float*)d_in[6];
  const float* Wa    = (const float*)d_in[7];
  const float* Qw    = (const float*)d_in[8];
  const float* Uf    = (const float*)d_in[9];
  const float* Ufb   = (const float*)d_in[10];
  const float* va    = (const float*)d_in[11];
  const float* vab   = (const float*)d_in[12];
  const float* Wyz   = (const float*)d_in[13];
  const float* Wyzb  = (const float*)d_in[14];
  const float* Wyr   = (const float*)d_in[15];
  const float* Wyrb  = (const float*)d_in[16];
  const float* Wyh   = (const float*)d_in[17];
  const float* Wyhb  = (const float*)d_in[18];
  const float* Uhz   = (const float*)d_in[19];
  const float* Uhr   = (const float*)d_in[20];
  const float* Uhh   = (const float*)d_in[21];
  const float* Wcz   = (const float*)d_in[22];
  const float* Wcr   = (const float*)d_in[23];
  const float* Wch   = (const float*)d_in[24];
  const float* Uhz2  = (const float*)d_in[25];
  const float* Uhz2b = (const float*)d_in[26];
  const float* Uhr2  = (const float*)d_in[27];
  const float* Uhr2b = (const float*)d_in[28];
  const float* Uhh2  = (const float*)d_in[29];
  const float* Uhh2b = (const float*)d_in[30];
  float* out = (float*)d_out;
  float* ws  = (float*)d_ws;

  k_prep<<<dim3(6292), dim3(256), 0, stream>>>(Uhz, Uhr, Uhh, Uhz2, Uhr2, Uhh2,
                                               Wyz, Wyr, Wyh, Wa, Wcz, Wcr, Wch, Ua, ws);
  k_kcomb<<<dim3(256), dim3(256), 0, stream>>>(Uf, Qw, ws);
  k_embproj<<<dim3(384), dim3(256), 0, stream>>>(emb, Wyzb, Wyrb, Wyhb, ws);
  k_uactx<<<dim3(768), dim3(256), 0, stream>>>(ctx, ws);
  k_step0<<<dim3(128), dim3(256), 0, stream>>>(inits, maskp, ws);

  k_cover<<<dim3(768), dim3(256), 0, stream>>>(va, Uab, Ufb, ws);
  k_alpha<<<dim3(688), dim3(256), 0, stream>>>(0, ctx, cmask, vab, out, ws);
  for (int t = 1; t < 48; ++t) {
    k_step1<<<dim3(128), dim3(256), 0, stream>>>(t, maskp, Uhz2b, Uhr2b, Uhh2b, out, ws);
    k_cover<<<dim3(768), dim3(256), 0, stream>>>(va, Uab, Ufb, ws);
    k_alpha<<<dim3(688), dim3(256), 0, stream>>>(t, ctx, cmask, vab, out, ws);
  }
  k_final<<<dim3(16), dim3(256), 0, stream>>>(maskp, Uhz2b, Uhr2b, Uhh2b, out, ws);
  (void)in_sizes; (void)n_in; (void)out_size; (void)ws_size;
}